// Round 1
// baseline (268.691 us; speedup 1.0000x reference)
//
#include <hip/hip_runtime.h>
#include <hip/hip_bf16.h>
#include <stdint.h>

#define S_LEN 2048
#define DIM   1024
#define NH    16
#define HD    64
#define BATCH 2

typedef __attribute__((ext_vector_type(4))) float f32x4;
typedef __attribute__((ext_vector_type(8))) short bf16x8;
typedef __hip_bfloat16 bf16;

__device__ inline void gload_lds16(const void* g, void* l) {
  __builtin_amdgcn_global_load_lds(
      (const __attribute__((address_space(1))) void*)g,
      (__attribute__((address_space(3))) void*)l, 16, 0, 0);
}

// ---------------- fp32 -> bf16 conversion ----------------
__global__ __launch_bounds__(256) void cvt_f32_bf16(
    const float* __restrict__ in, bf16* __restrict__ out, int n4) {
  int i = blockIdx.x * 256 + threadIdx.x;
  if (i >= n4) return;
  float4 v = ((const float4*)in)[i];
  bf16 b0 = __float2bfloat16(v.x), b1 = __float2bfloat16(v.y);
  bf16 b2 = __float2bfloat16(v.z), b3 = __float2bfloat16(v.w);
  ushort4 o;
  o.x = *(unsigned short*)&b0; o.y = *(unsigned short*)&b1;
  o.z = *(unsigned short*)&b2; o.w = *(unsigned short*)&b3;
  ((ushort4*)out)[i] = o;
}

// ---------------- GEMM: C[M,N] = A[M,K] * B[N,K]^T (m97 structure) ----------------
__device__ inline void storeC(float* C, size_t i, float v) { C[i] = v; }
__device__ inline void storeC(bf16* C, size_t i, float v)  { C[i] = __float2bfloat16(v); }

template <typename OutT>
__global__ __launch_bounds__(256) void gemm_bt(
    const bf16* __restrict__ A, const bf16* __restrict__ B,
    OutT* __restrict__ C, int M, int N, int K) {
  __shared__ __align__(16) bf16 Als[128 * 32];
  __shared__ __align__(16) bf16 Bls[128 * 32];
  const int tid = threadIdx.x;
  const int lane = tid & 63, wid = tid >> 6;
  const int wr = wid >> 1, wc = wid & 1;
  const int bm = blockIdx.y * 128, bn = blockIdx.x * 128;
  const int fr = lane & 15, fq = lane >> 4;

  f32x4 acc[4][4] = {};

  const int kTiles = K >> 5;
  for (int kt = 0; kt < kTiles; ++kt) {
    const int k0 = kt << 5;
    __syncthreads();
#pragma unroll
    for (int j = 0; j < 2; ++j) {
      int ob = wid * 2048 + j * 1024;   // wave-uniform LDS byte base
      int o = ob + lane * 16;           // this lane's byte
      int r = o >> 6;                   // tile row (64B per 32-elem row)
      int kk = (o & 63) >> 1;           // element within row
      gload_lds16(A + (size_t)(bm + r) * K + k0 + kk, (char*)Als + ob);
      gload_lds16(B + (size_t)(bn + r) * K + k0 + kk, (char*)Bls + ob);
    }
    __syncthreads();
    bf16x8 af[4], bfr[4];
#pragma unroll
    for (int m = 0; m < 4; ++m)
      af[m] = *(const bf16x8*)(Als + (wr * 64 + m * 16 + fr) * 32 + fq * 8);
#pragma unroll
    for (int n = 0; n < 4; ++n)
      bfr[n] = *(const bf16x8*)(Bls + (wc * 64 + n * 16 + fr) * 32 + fq * 8);
#pragma unroll
    for (int m = 0; m < 4; ++m)
#pragma unroll
      for (int n = 0; n < 4; ++n)
        acc[m][n] = __builtin_amdgcn_mfma_f32_16x16x32_bf16(af[m], bfr[n], acc[m][n], 0, 0, 0);
  }
#pragma unroll
  for (int m = 0; m < 4; ++m)
#pragma unroll
    for (int n = 0; n < 4; ++n)
#pragma unroll
      for (int i = 0; i < 4; ++i) {
        int row = bm + wr * 64 + m * 16 + fq * 4 + i;
        int col = bn + wc * 64 + n * 16 + fr;
        storeC(C, (size_t)row * N + col, acc[m][n][i]);
      }
}

// ---------------- V transpose: Vt[b][h][a][s] = KV[b*S+s][DIM + h*HD + a] ----------------
__global__ __launch_bounds__(256) void transpose_v(
    const bf16* __restrict__ KV, bf16* __restrict__ Vt) {
  __shared__ __align__(16) bf16 tile[64][72];
  const int t = threadIdx.x;
  const int s0 = blockIdx.x * 64, h = blockIdx.y, b = blockIdx.z;
#pragma unroll
  for (int j = 0; j < 2; ++j) {
    int s = j * 32 + (t >> 3);
    int a = (t & 7) * 8;
    bf16x8 v = *(const bf16x8*)(KV + (size_t)(b * S_LEN + s0 + s) * (2 * DIM) + DIM + h * HD + a);
    *(bf16x8*)&tile[s][a] = v;
  }
  __syncthreads();
#pragma unroll
  for (int j = 0; j < 2; ++j) {
    int a = j * 32 + (t >> 3);
    int sc = (t & 7) * 8;
    bf16x8 v;
#pragma unroll
    for (int e = 0; e < 8; ++e)
      ((short*)&v)[e] = *(const short*)&tile[sc + e][a];
    *(bf16x8*)(Vt + (size_t)((b * NH + h) * HD + a) * S_LEN + s0 + sc) = v;
  }
}

// ---------------- Flash attention (causal), bf16 MFMA ----------------
// grid: (S/64, NH, BATCH); 256 threads = 4 waves; wave handles 16 q rows.
__global__ __launch_bounds__(256) void attn_fwd(
    const bf16* __restrict__ Q,   // [B*S][DIM]
    const bf16* __restrict__ KV,  // [B*S][2*DIM] (K = first DIM cols)
    const bf16* __restrict__ Vt,  // [B*NH][HD][S]
    bf16* __restrict__ O) {       // [B*S][DIM]
  __shared__ __align__(16) bf16 Kls[32 * 64];     // [key][a], xor-swizzled
  __shared__ __align__(16) bf16 Vls[64 * 32];     // [a][key], xor-swizzled
  __shared__ __align__(16) bf16 Pls[4][16 * 32];  // per-wave P, xor-swizzled
  const int tid = threadIdx.x, lane = tid & 63, wid = tid >> 6;
  const int fr = lane & 15, fq = lane >> 4;
  const int qt = blockIdx.x, h = blockIdx.y, b = blockIdx.z;
  const int q0 = qt * 64 + wid * 16;
  const float scale = 0.03125f;  // 1/sqrt(1024)
  const float NEGINF = -__builtin_inff();

  // Q fragments (A operand), held in registers for the whole block
  bf16x8 qf[2];
#pragma unroll
  for (int kb = 0; kb < 2; ++kb)
    qf[kb] = *(const bf16x8*)(Q + (size_t)(b * S_LEN + q0 + fr) * DIM + h * HD + kb * 32 + fq * 8);

  f32x4 oacc[4] = {};
  float m_i[4], l_i[4];
#pragma unroll
  for (int i = 0; i < 4; ++i) { m_i[i] = NEGINF; l_i[i] = 0.f; }

  const int ntiles = (qt * 64 + 64) >> 5;  // causal bound for this block
  for (int kt = 0; kt < ntiles; ++kt) {
    __syncthreads();
    {
      int ob = wid * 1024;
      int o = ob + lane * 16;
      // K tile: rows of 128B; swizzle byte ^= (row&7)<<4 (pre-swizzled source)
      int r = o >> 7;
      int sbo = (o & 127) ^ ((r & 7) << 4);
      gload_lds16(KV + (size_t)(b * S_LEN + kt * 32 + r) * (2 * DIM) + h * HD + (sbo >> 1),
                  (char*)Kls + ob);
      // V tile: rows of 64B; swizzle byte ^= ((a>>1)&3)<<4
      int a = o >> 6;
      int vs = (o & 63) ^ (((a >> 1) & 3) << 4);
      gload_lds16(Vt + (size_t)((b * NH + h) * HD + a) * S_LEN + kt * 32 + (vs >> 1),
                  (char*)Vls + ob);
    }
    __syncthreads();

    // S = Q K^T  (2 key-column fragments of 16)
    f32x4 sfr[2] = {};
#pragma unroll
    for (int cf = 0; cf < 2; ++cf) {
#pragma unroll
      for (int kb = 0; kb < 2; ++kb) {
        int r = cf * 16 + fr;
        int x = kb * 64 + fq * 16;
        bf16x8 kf = *(const bf16x8*)((const char*)Kls + r * 128 + (x ^ ((r & 7) << 4)));
        sfr[cf] = __builtin_amdgcn_mfma_f32_16x16x32_bf16(qf[kb], kf, sfr[cf], 0, 0, 0);
      }
    }
    // logits + causal mask
    float p[2][4], tmax[4];
#pragma unroll
    for (int i = 0; i < 4; ++i) tmax[i] = NEGINF;
#pragma unroll
    for (int cf = 0; cf < 2; ++cf)
#pragma unroll
      for (int i = 0; i < 4; ++i) {
        int key = kt * 32 + cf * 16 + fr;
        int qrow = q0 + fq * 4 + i;
        float lg = (key <= qrow) ? sfr[cf][i] * scale : NEGINF;
        p[cf][i] = lg;
        tmax[i] = fmaxf(tmax[i], lg);
      }
#pragma unroll
    for (int d = 1; d < 16; d <<= 1)
#pragma unroll
      for (int i = 0; i < 4; ++i)
        tmax[i] = fmaxf(tmax[i], __shfl_xor(tmax[i], d));
    float fscale[4];
#pragma unroll
    for (int i = 0; i < 4; ++i) {
      float mn = fmaxf(m_i[i], tmax[i]);
      fscale[i] = __expf(m_i[i] - mn);  // exp(-inf - finite) = 0 on first tile
      m_i[i] = mn;
    }
    float psum[4] = {0.f, 0.f, 0.f, 0.f};
#pragma unroll
    for (int cf = 0; cf < 2; ++cf)
#pragma unroll
      for (int i = 0; i < 4; ++i) {
        float e = __expf(p[cf][i] - m_i[i]);  // masked -> exp(-inf) = 0
        p[cf][i] = e;
        psum[i] += e;
      }
#pragma unroll
    for (int d = 1; d < 16; d <<= 1)
#pragma unroll
      for (int i = 0; i < 4; ++i)
        psum[i] += __shfl_xor(psum[i], d);
#pragma unroll
    for (int i = 0; i < 4; ++i)
      l_i[i] = l_i[i] * fscale[i] + psum[i];
#pragma unroll
    for (int n = 0; n < 4; ++n)
#pragma unroll
      for (int i = 0; i < 4; ++i)
        oacc[n][i] *= fscale[i];

    // P -> LDS (bf16, swizzled), then PV
#pragma unroll
    for (int cf = 0; cf < 2; ++cf)
#pragma unroll
      for (int i = 0; i < 4; ++i) {
        int r = fq * 4 + i;
        int c = cf * 16 + fr;
        bf16 pb = __float2bfloat16(p[cf][i]);
        *(bf16*)((char*)Pls[wid] + r * 64 + ((c * 2) ^ (((r >> 1) & 3) << 4))) = pb;
      }
    {
      bf16x8 pa = *(const bf16x8*)((const char*)Pls[wid] + fr * 64 + ((fq * 16) ^ (((fr >> 1) & 3) << 4)));
#pragma unroll
      for (int n = 0; n < 4; ++n) {
        int a = n * 16 + fr;
        bf16x8 vf = *(const bf16x8*)((const char*)Vls + a * 64 + ((fq * 16) ^ (((a >> 1) & 3) << 4)));
        oacc[n] = __builtin_amdgcn_mfma_f32_16x16x32_bf16(pa, vf, oacc[n], 0, 0, 0);
      }
    }
  }
  // normalize + store
#pragma unroll
  for (int n = 0; n < 4; ++n)
#pragma unroll
    for (int i = 0; i < 4; ++i) {
      int qrow = q0 + fq * 4 + i;
      int col = h * HD + n * 16 + fr;
      float v = oacc[n][i] / l_i[i];
      O[(size_t)(b * S_LEN + qrow) * DIM + col] = __float2bfloat16(v);
    }
}

// ---------------- launch ----------------
extern "C" void kernel_launch(void* const* d_in, const int* in_sizes, int n_in,
                              void* d_out, int out_size, void* d_ws, size_t ws_size,
                              hipStream_t stream) {
  (void)in_sizes; (void)n_in; (void)out_size; (void)ws_size;
  const float* query   = (const float*)d_in[0];  // [B,S,D]
  const float* context = (const float*)d_in[1];  // [B,S,D]
  const float* Wq      = (const float*)d_in[2];  // [D,D]
  const float* Wkv     = (const float*)d_in[3];  // [2D,D]
  const float* Wout    = (const float*)d_in[4];  // [D,D]
  float* out = (float*)d_out;

  bf16* ws = (bf16*)d_ws;
  const size_t nBSD = (size_t)BATCH * S_LEN * DIM;  // 4194304
  bf16* qbf    = ws;
  bf16* cbf    = qbf + nBSD;
  bf16* wqbf   = cbf + nBSD;
  bf16* wkvbf  = wqbf + (size_t)DIM * DIM;
  bf16* woutbf = wkvbf + (size_t)2 * DIM * DIM;
  bf16* Qp     = woutbf + (size_t)DIM * DIM;
  bf16* KVp    = Qp + nBSD;
  bf16* Vtp    = KVp + 2 * nBSD;
  bf16* Op     = Vtp + nBSD;

  // conversions
  cvt_f32_bf16<<<(int)(nBSD / 1024), 256, 0, stream>>>(query, qbf, (int)(nBSD / 4));
  cvt_f32_bf16<<<(int)(nBSD / 1024), 256, 0, stream>>>(context, cbf, (int)(nBSD / 4));
  cvt_f32_bf16<<<DIM * DIM / 1024, 256, 0, stream>>>(Wq, wqbf, DIM * DIM / 4);
  cvt_f32_bf16<<<2 * DIM * DIM / 1024, 256, 0, stream>>>(Wkv, wkvbf, 2 * DIM * DIM / 4);
  cvt_f32_bf16<<<DIM * DIM / 1024, 256, 0, stream>>>(Wout, woutbf, DIM * DIM / 4);

  const int M = BATCH * S_LEN;  // 4096
  // Q = query * Wq^T
  gemm_bt<bf16><<<dim3(DIM / 128, M / 128), 256, 0, stream>>>(qbf, wqbf, Qp, M, DIM, DIM);
  // KV = context * Wkv^T
  gemm_bt<bf16><<<dim3(2 * DIM / 128, M / 128), 256, 0, stream>>>(cbf, wkvbf, KVp, M, 2 * DIM, DIM);
  // Vt
  transpose_v<<<dim3(S_LEN / 64, NH, BATCH), 256, 0, stream>>>(KVp, Vtp);
  // attention
  attn_fwd<<<dim3(S_LEN / 64, NH, BATCH), 256, 0, stream>>>(Qp, KVp, Vtp, Op);
  // out = O * Wout^T
  gemm_bt<float><<<dim3(DIM / 128, M / 128), 256, 0, stream>>>(Op, woutbf, out, M, DIM, DIM);
}

// Round 2
// 227.769 us; speedup vs baseline: 1.1797x; 1.1797x over previous
//
#include <hip/hip_runtime.h>
#include <hip/hip_bf16.h>
#include <stdint.h>

#define S_LEN 2048
#define DIM   1024
#define NH    16
#define HD    64
#define BATCH 2

typedef __attribute__((ext_vector_type(4))) float f32x4;
typedef __attribute__((ext_vector_type(8))) short bf16x8;
typedef __hip_bfloat16 bf16;

__device__ inline void gload_lds16(const void* g, void* l) {
  __builtin_amdgcn_global_load_lds(
      (const __attribute__((address_space(1))) void*)g,
      (__attribute__((address_space(3))) void*)l, 16, 0, 0);
}

// ---------------- fp32 -> bf16 conversion ----------------
__global__ __launch_bounds__(256) void cvt_f32_bf16(
    const float* __restrict__ in, bf16* __restrict__ out, int n4) {
  int i = blockIdx.x * 256 + threadIdx.x;
  if (i >= n4) return;
  float4 v = ((const float4*)in)[i];
  bf16 b0 = __float2bfloat16(v.x), b1 = __float2bfloat16(v.y);
  bf16 b2 = __float2bfloat16(v.z), b3 = __float2bfloat16(v.w);
  ushort4 o;
  o.x = *(unsigned short*)&b0; o.y = *(unsigned short*)&b1;
  o.z = *(unsigned short*)&b2; o.w = *(unsigned short*)&b3;
  ((ushort4*)out)[i] = o;
}

// ---------------- GEMM: C[M,N] = alpha * A[M,K] * B[N,K]^T (m97 structure) ----------------
__device__ inline void storeC(float* C, size_t i, float v) { C[i] = v; }
__device__ inline void storeC(bf16* C, size_t i, float v)  { C[i] = __float2bfloat16(v); }

template <typename OutT>
__global__ __launch_bounds__(256) void gemm_bt(
    const bf16* __restrict__ A, const bf16* __restrict__ B,
    OutT* __restrict__ C, int M, int N, int K, float alpha) {
  __shared__ __align__(16) bf16 Als[128 * 32];
  __shared__ __align__(16) bf16 Bls[128 * 32];
  const int tid = threadIdx.x;
  const int lane = tid & 63, wid = tid >> 6;
  const int wr = wid >> 1, wc = wid & 1;
  const int bm = blockIdx.y * 128, bn = blockIdx.x * 128;
  const int fr = lane & 15, fq = lane >> 4;

  f32x4 acc[4][4] = {};

  const int kTiles = K >> 5;
  for (int kt = 0; kt < kTiles; ++kt) {
    const int k0 = kt << 5;
    __syncthreads();
#pragma unroll
    for (int j = 0; j < 2; ++j) {
      int ob = wid * 2048 + j * 1024;   // wave-uniform LDS byte base
      int o = ob + lane * 16;           // this lane's byte
      int r = o >> 6;                   // tile row (64B per 32-elem row)
      int kk = (o & 63) >> 1;           // element within row
      gload_lds16(A + (size_t)(bm + r) * K + k0 + kk, (char*)Als + ob);
      gload_lds16(B + (size_t)(bn + r) * K + k0 + kk, (char*)Bls + ob);
    }
    __syncthreads();
    bf16x8 af[4], bfr[4];
#pragma unroll
    for (int m = 0; m < 4; ++m)
      af[m] = *(const bf16x8*)(Als + (wr * 64 + m * 16 + fr) * 32 + fq * 8);
#pragma unroll
    for (int n = 0; n < 4; ++n)
      bfr[n] = *(const bf16x8*)(Bls + (wc * 64 + n * 16 + fr) * 32 + fq * 8);
#pragma unroll
    for (int m = 0; m < 4; ++m)
#pragma unroll
      for (int n = 0; n < 4; ++n)
        acc[m][n] = __builtin_amdgcn_mfma_f32_16x16x32_bf16(af[m], bfr[n], acc[m][n], 0, 0, 0);
  }
#pragma unroll
  for (int m = 0; m < 4; ++m)
#pragma unroll
    for (int n = 0; n < 4; ++n)
#pragma unroll
      for (int i = 0; i < 4; ++i) {
        int row = bm + wr * 64 + m * 16 + fq * 4 + i;
        int col = bn + wc * 64 + n * 16 + fr;
        storeC(C, (size_t)row * N + col, acc[m][n][i] * alpha);
      }
}

// ---------------- V transpose: Vt[b][h][a][s] = KV[b*S+s][DIM + h*HD + a] ----------------
__global__ __launch_bounds__(256) void transpose_v(
    const bf16* __restrict__ KV, bf16* __restrict__ Vt) {
  __shared__ __align__(16) bf16 tile[64][72];
  const int t = threadIdx.x;
  const int s0 = blockIdx.x * 64, h = blockIdx.y, b = blockIdx.z;
#pragma unroll
  for (int j = 0; j < 2; ++j) {
    int s = j * 32 + (t >> 3);
    int a = (t & 7) * 8;
    bf16x8 v = *(const bf16x8*)(KV + (size_t)(b * S_LEN + s0 + s) * (2 * DIM) + DIM + h * HD + a);
    *(bf16x8*)&tile[s][a] = v;
  }
  __syncthreads();
#pragma unroll
  for (int j = 0; j < 2; ++j) {
    int a = j * 32 + (t >> 3);
    int sc = (t & 7) * 8;
    bf16x8 v;
#pragma unroll
    for (int e = 0; e < 8; ++e)
      ((short*)&v)[e] = *(const short*)&tile[sc + e][a];
    *(bf16x8*)(Vt + (size_t)((b * NH + h) * HD + a) * S_LEN + s0 + sc) = v;
  }
}

// ---------------- Flash attention (causal), bf16 MFMA, KVBLK=64, double-buffered ----------------
// grid: (S/64, NH, BATCH); 256 threads = 4 waves; wave handles 16 q rows.
// Q is pre-scaled by 1/sqrt(D) in the Q-projection epilogue.
__global__ __launch_bounds__(256) void attn_fwd(
    const bf16* __restrict__ Q,   // [B*S][DIM] (pre-scaled)
    const bf16* __restrict__ KV,  // [B*S][2*DIM] (K = first DIM cols)
    const bf16* __restrict__ Vt,  // [B*NH][HD][S]
    bf16* __restrict__ O) {       // [B*S][DIM]
  __shared__ __align__(16) bf16 Kls[2][64 * 64];  // [key][a], xor-swizzled rows (128B)
  __shared__ __align__(16) bf16 Vls[2][64 * 64];  // [a][key], xor-swizzled rows (128B)
  __shared__ __align__(16) bf16 Pls[4][16 * 64];  // per-wave P [q][key], swizzled
  const int tid = threadIdx.x, lane = tid & 63, wid = tid >> 6;
  const int fr = lane & 15, fq = lane >> 4;
  const int qt = blockIdx.x, h = blockIdx.y, b = blockIdx.z;
  const int q0 = qt * 64 + wid * 16;
  const float NEGINF = -__builtin_inff();

  // Q fragments (A operand), registers for the whole block
  bf16x8 qf[2];
#pragma unroll
  for (int kb = 0; kb < 2; ++kb)
    qf[kb] = *(const bf16x8*)(Q + (size_t)(b * S_LEN + q0 + fr) * DIM + h * HD + kb * 32 + fq * 8);

  f32x4 oacc[4] = {};
  float m_i[4], l_i[4];
#pragma unroll
  for (int i = 0; i < 4; ++i) { m_i[i] = NEGINF; l_i[i] = 0.f; }

  // staging: one 64-key tile = 8KB each for K and V; 4 waves x 2 rounds x 1KB
  auto stage = [&](int buf, int kt) {
#pragma unroll
    for (int j = 0; j < 2; ++j) {
      int ob = (wid * 2 + j) * 1024;
      int o = ob + lane * 16;
      int r = o >> 7;                              // row (key for K, a for V)
      int sb = (o & 127) ^ ((r & 7) << 4);         // pre-swizzled byte within row
      gload_lds16(KV + (size_t)(b * S_LEN + kt * 64 + r) * (2 * DIM) + h * HD + (sb >> 1),
                  (char*)Kls[buf] + ob);
      gload_lds16(Vt + (size_t)((b * NH + h) * HD + r) * S_LEN + kt * 64 + (sb >> 1),
                  (char*)Vls[buf] + ob);
    }
  };

  const int nt = qt + 1;  // causal bound, 64-key tiles
  int cur = 0;
  stage(0, 0);
  asm volatile("s_waitcnt vmcnt(0)" ::: "memory");
  __syncthreads();

  for (int kt = 0; kt < nt; ++kt) {
    if (kt + 1 < nt) stage(cur ^ 1, kt + 1);  // async prefetch, overlaps compute

    const bf16* Kb = Kls[cur];
    const bf16* Vb = Vls[cur];

    // ---- S = Q K^T (4 key-col frags of 16) ----
    f32x4 sfr[4];
#pragma unroll
    for (int cf = 0; cf < 4; ++cf) sfr[cf] = (f32x4){0.f, 0.f, 0.f, 0.f};
    __builtin_amdgcn_s_setprio(1);
#pragma unroll
    for (int cf = 0; cf < 4; ++cf) {
      int r = cf * 16 + fr;
#pragma unroll
      for (int kb = 0; kb < 2; ++kb) {
        bf16x8 kf = *(const bf16x8*)((const char*)Kb + r * 128 + ((kb * 64 + fq * 16) ^ ((r & 7) << 4)));
        sfr[cf] = __builtin_amdgcn_mfma_f32_16x16x32_bf16(qf[kb], kf, sfr[cf], 0, 0, 0);
      }
    }
    __builtin_amdgcn_s_setprio(0);

    // ---- logits + (diagonal-only) causal mask + online softmax ----
    float p[4][4], tmax[4];
#pragma unroll
    for (int i = 0; i < 4; ++i) tmax[i] = NEGINF;
    if (kt == qt) {  // diagonal tile: mask
#pragma unroll
      for (int cf = 0; cf < 4; ++cf)
#pragma unroll
        for (int i = 0; i < 4; ++i) {
          int key = kt * 64 + cf * 16 + fr;
          int qrow = q0 + fq * 4 + i;
          float lg = (key <= qrow) ? sfr[cf][i] : NEGINF;
          p[cf][i] = lg;
          tmax[i] = fmaxf(tmax[i], lg);
        }
    } else {
#pragma unroll
      for (int cf = 0; cf < 4; ++cf)
#pragma unroll
        for (int i = 0; i < 4; ++i) {
          p[cf][i] = sfr[cf][i];
          tmax[i] = fmaxf(tmax[i], sfr[cf][i]);
        }
    }
#pragma unroll
    for (int d = 1; d < 16; d <<= 1)
#pragma unroll
      for (int i = 0; i < 4; ++i)
        tmax[i] = fmaxf(tmax[i], __shfl_xor(tmax[i], d));
    float fscale[4];
#pragma unroll
    for (int i = 0; i < 4; ++i) {
      float mn = fmaxf(m_i[i], tmax[i]);
      fscale[i] = __expf(m_i[i] - mn);
      m_i[i] = mn;
    }
    float psum[4] = {0.f, 0.f, 0.f, 0.f};
#pragma unroll
    for (int cf = 0; cf < 4; ++cf)
#pragma unroll
      for (int i = 0; i < 4; ++i) {
        float e = __expf(p[cf][i] - m_i[i]);
        p[cf][i] = e;
        psum[i] += e;
      }
#pragma unroll
    for (int d = 1; d < 16; d <<= 1)
#pragma unroll
      for (int i = 0; i < 4; ++i)
        psum[i] += __shfl_xor(psum[i], d);
#pragma unroll
    for (int i = 0; i < 4; ++i)
      l_i[i] = l_i[i] * fscale[i] + psum[i];
#pragma unroll
    for (int n = 0; n < 4; ++n)
#pragma unroll
      for (int i = 0; i < 4; ++i)
        oacc[n][i] *= fscale[i];

    // ---- P -> per-wave LDS (swizzled), then PV ----
#pragma unroll
    for (int cf = 0; cf < 4; ++cf)
#pragma unroll
      for (int i = 0; i < 4; ++i) {
        int r = fq * 4 + i;
        int c = cf * 16 + fr;
        bf16 pb = __float2bfloat16(p[cf][i]);
        *(bf16*)((char*)Pls[wid] + r * 128 + ((c * 2) ^ ((r & 7) << 4))) = pb;
      }
    __builtin_amdgcn_s_setprio(1);
#pragma unroll
    for (int kk = 0; kk < 2; ++kk) {
      bf16x8 pa = *(const bf16x8*)((const char*)Pls[wid] + fr * 128 + ((kk * 64 + fq * 16) ^ ((fr & 7) << 4)));
#pragma unroll
      for (int n = 0; n < 4; ++n) {
        int a = n * 16 + fr;
        bf16x8 vf = *(const bf16x8*)((const char*)Vb + a * 128 + ((kk * 64 + fq * 16) ^ ((a & 7) << 4)));
        oacc[n] = __builtin_amdgcn_mfma_f32_16x16x32_bf16(pa, vf, oacc[n], 0, 0, 0);
      }
    }
    __builtin_amdgcn_s_setprio(0);

    asm volatile("s_waitcnt vmcnt(0)" ::: "memory");  // next tile's staging landed
    __syncthreads();
    cur ^= 1;
  }

  // ---- normalize + store ----
#pragma unroll
  for (int n = 0; n < 4; ++n)
#pragma unroll
    for (int i = 0; i < 4; ++i) {
      int qrow = q0 + fq * 4 + i;
      int col = h * HD + n * 16 + fr;
      float v = oacc[n][i] / l_i[i];
      O[(size_t)(b * S_LEN + qrow) * DIM + col] = __float2bfloat16(v);
    }
}

// ---------------- launch ----------------
extern "C" void kernel_launch(void* const* d_in, const int* in_sizes, int n_in,
                              void* d_out, int out_size, void* d_ws, size_t ws_size,
                              hipStream_t stream) {
  (void)in_sizes; (void)n_in; (void)out_size; (void)ws_size;
  const float* query   = (const float*)d_in[0];  // [B,S,D]
  const float* context = (const float*)d_in[1];  // [B,S,D]
  const float* Wq      = (const float*)d_in[2];  // [D,D]
  const float* Wkv     = (const float*)d_in[3];  // [2D,D]
  const float* Wout    = (const float*)d_in[4];  // [D,D]
  float* out = (float*)d_out;

  bf16* ws = (bf16*)d_ws;
  const size_t nBSD = (size_t)BATCH * S_LEN * DIM;  // 4194304
  bf16* qbf    = ws;
  bf16* cbf    = qbf + nBSD;
  bf16* wqbf   = cbf + nBSD;
  bf16* wkvbf  = wqbf + (size_t)DIM * DIM;
  bf16* woutbf = wkvbf + (size_t)2 * DIM * DIM;
  bf16* Qp     = woutbf + (size_t)DIM * DIM;
  bf16* KVp    = Qp + nBSD;
  bf16* Vtp    = KVp + 2 * nBSD;
  bf16* Op     = Vtp + nBSD;

  // conversions
  cvt_f32_bf16<<<(int)(nBSD / 1024), 256, 0, stream>>>(query, qbf, (int)(nBSD / 4));
  cvt_f32_bf16<<<(int)(nBSD / 1024), 256, 0, stream>>>(context, cbf, (int)(nBSD / 4));
  cvt_f32_bf16<<<DIM * DIM / 1024, 256, 0, stream>>>(Wq, wqbf, DIM * DIM / 4);
  cvt_f32_bf16<<<2 * DIM * DIM / 1024, 256, 0, stream>>>(Wkv, wkvbf, 2 * DIM * DIM / 4);
  cvt_f32_bf16<<<DIM * DIM / 1024, 256, 0, stream>>>(Wout, woutbf, DIM * DIM / 4);

  const int M = BATCH * S_LEN;  // 4096
  // Q = (query * Wq^T) * (1/sqrt(D))  -- scale folded into epilogue
  gemm_bt<bf16><<<dim3(DIM / 128, M / 128), 256, 0, stream>>>(qbf, wqbf, Qp, M, DIM, DIM, 0.03125f);
  // KV = context * Wkv^T
  gemm_bt<bf16><<<dim3(2 * DIM / 128, M / 128), 256, 0, stream>>>(cbf, wkvbf, KVp, M, 2 * DIM, DIM, 1.0f);
  // Vt
  transpose_v<<<dim3(S_LEN / 64, NH, BATCH), 256, 0, stream>>>(KVp, Vtp);
  // attention
  attn_fwd<<<dim3(S_LEN / 64, NH, BATCH), 256, 0, stream>>>(Qp, KVp, Vtp, Op);
  // out = O * Wout^T
  gemm_bt<float><<<dim3(DIM / 128, M / 128), 256, 0, stream>>>(Op, woutbf, out, M, DIM, DIM, 1.0f);
}

// Round 3
// 174.341 us; speedup vs baseline: 1.5412x; 1.3065x over previous
//
#include <hip/hip_runtime.h>
#include <hip/hip_bf16.h>
#include <stdint.h>

#define S_LEN 2048
#define DIM   1024
#define NH    16
#define HD    64
#define BATCH 2

typedef __attribute__((ext_vector_type(4))) float f32x4;
typedef __attribute__((ext_vector_type(8))) short bf16x8;
typedef __hip_bfloat16 bf16;

__device__ inline void gload_lds16(const void* g, void* l) {
  __builtin_amdgcn_global_load_lds(
      (const __attribute__((address_space(1))) void*)g,
      (__attribute__((address_space(3))) void*)l, 16, 0, 0);
}

// ---------------- fp32 -> bf16 conversion ----------------
__global__ __launch_bounds__(256) void cvt_f32_bf16(
    const float* __restrict__ in, bf16* __restrict__ out, int n4) {
  int i = blockIdx.x * 256 + threadIdx.x;
  if (i >= n4) return;
  float4 v = ((const float4*)in)[i];
  bf16 b0 = __float2bfloat16(v.x), b1 = __float2bfloat16(v.y);
  bf16 b2 = __float2bfloat16(v.z), b3 = __float2bfloat16(v.w);
  ushort4 o;
  o.x = *(unsigned short*)&b0; o.y = *(unsigned short*)&b1;
  o.z = *(unsigned short*)&b2; o.w = *(unsigned short*)&b3;
  ((ushort4*)out)[i] = o;
}

// ---------------- GEMM: C[M,N] = alpha * A[M,K] * B[N,K]^T (m97 structure) ----------------
__device__ inline void storeC(float* C, size_t i, float v) { C[i] = v; }
__device__ inline void storeC(bf16* C, size_t i, float v)  { C[i] = __float2bfloat16(v); }

template <typename OutT>
__global__ __launch_bounds__(256) void gemm_bt(
    const bf16* __restrict__ A, const bf16* __restrict__ B,
    OutT* __restrict__ C, int M, int N, int K, float alpha) {
  __shared__ __align__(16) bf16 Als[128 * 32];
  __shared__ __align__(16) bf16 Bls[128 * 32];
  const int tid = threadIdx.x;
  const int lane = tid & 63, wid = tid >> 6;
  const int wr = wid >> 1, wc = wid & 1;
  const int bm = blockIdx.y * 128, bn = blockIdx.x * 128;
  const int fr = lane & 15, fq = lane >> 4;

  f32x4 acc[4][4] = {};

  const int kTiles = K >> 5;
  for (int kt = 0; kt < kTiles; ++kt) {
    const int k0 = kt << 5;
    __syncthreads();
#pragma unroll
    for (int j = 0; j < 2; ++j) {
      int ob = wid * 2048 + j * 1024;   // wave-uniform LDS byte base
      int o = ob + lane * 16;           // this lane's byte
      int r = o >> 6;                   // tile row (64B per 32-elem row)
      int kk = (o & 63) >> 1;           // element within row
      gload_lds16(A + (size_t)(bm + r) * K + k0 + kk, (char*)Als + ob);
      gload_lds16(B + (size_t)(bn + r) * K + k0 + kk, (char*)Bls + ob);
    }
    __syncthreads();
    bf16x8 af[4], bfr[4];
#pragma unroll
    for (int m = 0; m < 4; ++m)
      af[m] = *(const bf16x8*)(Als + (wr * 64 + m * 16 + fr) * 32 + fq * 8);
#pragma unroll
    for (int n = 0; n < 4; ++n)
      bfr[n] = *(const bf16x8*)(Bls + (wc * 64 + n * 16 + fr) * 32 + fq * 8);
#pragma unroll
    for (int m = 0; m < 4; ++m)
#pragma unroll
      for (int n = 0; n < 4; ++n)
        acc[m][n] = __builtin_amdgcn_mfma_f32_16x16x32_bf16(af[m], bfr[n], acc[m][n], 0, 0, 0);
  }
#pragma unroll
  for (int m = 0; m < 4; ++m)
#pragma unroll
    for (int n = 0; n < 4; ++n)
#pragma unroll
      for (int i = 0; i < 4; ++i) {
        int row = bm + wr * 64 + m * 16 + fq * 4 + i;
        int col = bn + wc * 64 + n * 16 + fr;
        storeC(C, (size_t)row * N + col, acc[m][n][i] * alpha);
      }
}

// ---------------- V transpose: Vt[b][h][a][s] = KV[b*S+s][DIM + h*HD + a] ----------------
__global__ __launch_bounds__(256) void transpose_v(
    const bf16* __restrict__ KV, bf16* __restrict__ Vt) {
  __shared__ __align__(16) bf16 tile[64][72];
  const int t = threadIdx.x;
  const int s0 = blockIdx.x * 64, h = blockIdx.y, b = blockIdx.z;
#pragma unroll
  for (int j = 0; j < 2; ++j) {
    int s = j * 32 + (t >> 3);
    int a = (t & 7) * 8;
    bf16x8 v = *(const bf16x8*)(KV + (size_t)(b * S_LEN + s0 + s) * (2 * DIM) + DIM + h * HD + a);
    *(bf16x8*)&tile[s][a] = v;
  }
  __syncthreads();
#pragma unroll
  for (int j = 0; j < 2; ++j) {
    int a = j * 32 + (t >> 3);
    int sc = (t & 7) * 8;
    bf16x8 v;
#pragma unroll
    for (int e = 0; e < 8; ++e)
      ((short*)&v)[e] = *(const short*)&tile[sc + e][a];
    *(bf16x8*)(Vt + (size_t)((b * NH + h) * HD + a) * S_LEN + s0 + sc) = v;
  }
}

// ---------------- Flash attention (causal), no-max softmax, deferred row-sum ----------------
// grid: (S/128, NH, BATCH) with heavy-first remap; 256 threads = 4 waves; wave = 32 q rows.
// Q is pre-scaled by log2(e)/sqrt(D); P = exp2(S) directly; row-sum reduced once at the end.
__global__ __launch_bounds__(256) void attn_fwd(
    const bf16* __restrict__ Q,   // [B*S][DIM] (pre-scaled by log2e/32)
    const bf16* __restrict__ KV,  // [B*S][2*DIM] (K = first DIM cols)
    const bf16* __restrict__ Vt,  // [B*NH][HD][S]
    bf16* __restrict__ O) {       // [B*S][DIM]
  __shared__ __align__(16) bf16 Kls[2][64 * 64];  // [key][a], 128B rows, xor-swizzled
  __shared__ __align__(16) bf16 Vls[2][64 * 64];  // [a][key], 128B rows, xor-swizzled
  __shared__ __align__(16) bf16 Pls[4][32 * 64];  // per-wave P [q][key], swizzled
  const int tid = threadIdx.x, lane = tid & 63, wid = tid >> 6;
  const int fr = lane & 15, fq = lane >> 4;
  const int qx = (int)gridDim.x - 1 - blockIdx.x;  // heavy tiles first
  const int h = blockIdx.y, b = blockIdx.z;
  const int rw0 = qx * 128 + wid * 32;  // wave's first q row (within sequence)
  const float NEGINF = -__builtin_inff();

  // Q fragments: qf[m][kb] for q-sub-blocks m=0,1 and HD halves kb=0,1
  bf16x8 qf[2][2];
#pragma unroll
  for (int m = 0; m < 2; ++m)
#pragma unroll
    for (int kb = 0; kb < 2; ++kb)
      qf[m][kb] = *(const bf16x8*)(Q + (size_t)(b * S_LEN + rw0 + m * 16 + fr) * DIM +
                                   h * HD + kb * 32 + fq * 8);

  f32x4 oacc[2][4] = {};
  float rsum[2][4] = {};

  auto stage = [&](int buf, int kt) {
#pragma unroll
    for (int j = 0; j < 2; ++j) {
      int ob = (wid * 2 + j) * 1024;
      int o = ob + lane * 16;
      int r = o >> 7;                       // row (key for K, a for V)
      int sb = (o & 127) ^ ((r & 7) << 4);  // pre-swizzled byte within row
      gload_lds16(KV + (size_t)(b * S_LEN + kt * 64 + r) * (2 * DIM) + h * HD + (sb >> 1),
                  (char*)Kls[buf] + ob);
      gload_lds16(Vt + (size_t)((b * NH + h) * HD + r) * S_LEN + kt * 64 + (sb >> 1),
                  (char*)Vls[buf] + ob);
    }
  };

  const int nt = 2 * qx + 2;  // causal bound in 64-key tiles
  int cur = 0;
  stage(0, 0);
  asm volatile("s_waitcnt vmcnt(0)" ::: "memory");
  __syncthreads();

  for (int kt = 0; kt < nt; ++kt) {
    if (kt + 1 < nt) stage(cur ^ 1, kt + 1);  // async prefetch under compute

    const bf16* Kb = Kls[cur];
    const bf16* Vb = Vls[cur];

    // ---- K fragments (shared across both q-sub-blocks) ----
    bf16x8 kf[4][2];
#pragma unroll
    for (int cf = 0; cf < 4; ++cf) {
      int r = cf * 16 + fr;
#pragma unroll
      for (int kb = 0; kb < 2; ++kb)
        kf[cf][kb] = *(const bf16x8*)((const char*)Kb + r * 128 +
                                      ((kb * 64 + fq * 16) ^ ((r & 7) << 4)));
    }
    // ---- S = Q K^T ----
    f32x4 sfr[2][4];
#pragma unroll
    for (int m = 0; m < 2; ++m)
#pragma unroll
      for (int cf = 0; cf < 4; ++cf) sfr[m][cf] = (f32x4){0.f, 0.f, 0.f, 0.f};
    __builtin_amdgcn_s_setprio(1);
#pragma unroll
    for (int m = 0; m < 2; ++m)
#pragma unroll
      for (int cf = 0; cf < 4; ++cf)
#pragma unroll
        for (int kb = 0; kb < 2; ++kb)
          sfr[m][cf] = __builtin_amdgcn_mfma_f32_16x16x32_bf16(qf[m][kb], kf[cf][kb], sfr[m][cf], 0, 0, 0);
    __builtin_amdgcn_s_setprio(0);

    // ---- P = exp2(S) (no max), accumulate per-lane row sums, write P to LDS ----
    const bool maskt = (64 * kt + 63 > rw0);  // wave-uniform
#pragma unroll
    for (int m = 0; m < 2; ++m)
#pragma unroll
      for (int cf = 0; cf < 4; ++cf)
#pragma unroll
        for (int i = 0; i < 4; ++i) {
          float s = sfr[m][cf][i];
          if (maskt) {
            int key = 64 * kt + cf * 16 + fr;
            int qrow = rw0 + m * 16 + fq * 4 + i;
            if (key > qrow) s = NEGINF;
          }
          float pe = __builtin_amdgcn_exp2f(s);
          rsum[m][i] += pe;
          int r = m * 16 + fq * 4 + i;
          int c = cf * 16 + fr;
          bf16 pb = __float2bfloat16(pe);
          *(bf16*)((char*)Pls[wid] + r * 128 + ((c * 2) ^ ((r & 7) << 4))) = pb;
        }

    // ---- PV ----
    __builtin_amdgcn_s_setprio(1);
#pragma unroll
    for (int kk = 0; kk < 2; ++kk) {
      bf16x8 pa[2];
#pragma unroll
      for (int m = 0; m < 2; ++m)
        pa[m] = *(const bf16x8*)((const char*)Pls[wid] + (m * 16 + fr) * 128 +
                                 ((kk * 64 + fq * 16) ^ ((fr & 7) << 4)));
#pragma unroll
      for (int n = 0; n < 4; ++n) {
        int a = n * 16 + fr;
        bf16x8 vf = *(const bf16x8*)((const char*)Vb + a * 128 +
                                     ((kk * 64 + fq * 16) ^ ((a & 7) << 4)));
#pragma unroll
        for (int m = 0; m < 2; ++m)
          oacc[m][n] = __builtin_amdgcn_mfma_f32_16x16x32_bf16(pa[m], vf, oacc[m][n], 0, 0, 0);
      }
    }
    __builtin_amdgcn_s_setprio(0);

    asm volatile("s_waitcnt vmcnt(0)" ::: "memory");  // prefetch landed
    __syncthreads();
    cur ^= 1;
  }

  // ---- one-time row-sum reduce over the 16 key-lanes, normalize, store ----
#pragma unroll
  for (int d = 1; d < 16; d <<= 1)
#pragma unroll
    for (int m = 0; m < 2; ++m)
#pragma unroll
      for (int i = 0; i < 4; ++i)
        rsum[m][i] += __shfl_xor(rsum[m][i], d);
  float rinv[2][4];
#pragma unroll
  for (int m = 0; m < 2; ++m)
#pragma unroll
    for (int i = 0; i < 4; ++i) rinv[m][i] = 1.0f / rsum[m][i];
#pragma unroll
  for (int m = 0; m < 2; ++m)
#pragma unroll
    for (int n = 0; n < 4; ++n)
#pragma unroll
      for (int i = 0; i < 4; ++i) {
        int qrow = rw0 + m * 16 + fq * 4 + i;
        int col = h * HD + n * 16 + fr;
        O[(size_t)(b * S_LEN + qrow) * DIM + col] = __float2bfloat16(oacc[m][n][i] * rinv[m][i]);
      }
}

// ---------------- launch ----------------
extern "C" void kernel_launch(void* const* d_in, const int* in_sizes, int n_in,
                              void* d_out, int out_size, void* d_ws, size_t ws_size,
                              hipStream_t stream) {
  (void)in_sizes; (void)n_in; (void)out_size; (void)ws_size;
  const float* query   = (const float*)d_in[0];  // [B,S,D]
  const float* context = (const float*)d_in[1];  // [B,S,D]
  const float* Wq      = (const float*)d_in[2];  // [D,D]
  const float* Wkv     = (const float*)d_in[3];  // [2D,D]
  const float* Wout    = (const float*)d_in[4];  // [D,D]
  float* out = (float*)d_out;

  bf16* ws = (bf16*)d_ws;
  const size_t nBSD = (size_t)BATCH * S_LEN * DIM;  // 4194304
  bf16* qbf    = ws;
  bf16* cbf    = qbf + nBSD;
  bf16* wqbf   = cbf + nBSD;
  bf16* wkvbf  = wqbf + (size_t)DIM * DIM;
  bf16* woutbf = wkvbf + (size_t)2 * DIM * DIM;
  bf16* Qp     = woutbf + (size_t)DIM * DIM;
  bf16* KVp    = Qp + nBSD;
  bf16* Vtp    = KVp + 2 * nBSD;
  bf16* Op     = Vtp + nBSD;

  // conversions
  cvt_f32_bf16<<<(int)(nBSD / 1024), 256, 0, stream>>>(query, qbf, (int)(nBSD / 4));
  cvt_f32_bf16<<<(int)(nBSD / 1024), 256, 0, stream>>>(context, cbf, (int)(nBSD / 4));
  cvt_f32_bf16<<<DIM * DIM / 1024, 256, 0, stream>>>(Wq, wqbf, DIM * DIM / 4);
  cvt_f32_bf16<<<2 * DIM * DIM / 1024, 256, 0, stream>>>(Wkv, wkvbf, 2 * DIM * DIM / 4);
  cvt_f32_bf16<<<DIM * DIM / 1024, 256, 0, stream>>>(Wout, woutbf, DIM * DIM / 4);

  const int M = BATCH * S_LEN;  // 4096
  // Q = (query * Wq^T) * (log2(e)/sqrt(D))  -- softmax becomes exp2 directly
  gemm_bt<bf16><<<dim3(DIM / 128, M / 128), 256, 0, stream>>>(qbf, wqbf, Qp, M, DIM, DIM,
                                                              0.0450842200277801f);
  // KV = context * Wkv^T
  gemm_bt<bf16><<<dim3(2 * DIM / 128, M / 128), 256, 0, stream>>>(cbf, wkvbf, KVp, M, 2 * DIM, DIM, 1.0f);
  // Vt
  transpose_v<<<dim3(S_LEN / 64, NH, BATCH), 256, 0, stream>>>(KVp, Vtp);
  // attention
  attn_fwd<<<dim3(S_LEN / 128, NH, BATCH), 256, 0, stream>>>(Qp, KVp, Vtp, Op);
  // out = O * Wout^T
  gemm_bt<float><<<dim3(DIM / 128, M / 128), 256, 0, stream>>>(Op, woutbf, out, M, DIM, DIM, 1.0f);
}

// Round 4
// 156.799 us; speedup vs baseline: 1.7136x; 1.1119x over previous
//
#include <hip/hip_runtime.h>
#include <hip/hip_bf16.h>
#include <stdint.h>

#define S_LEN 2048
#define DIM   1024
#define NH    16
#define HD    64
#define BATCH 2

typedef __attribute__((ext_vector_type(4))) float f32x4;
typedef __attribute__((ext_vector_type(16))) float f32x16;
typedef __attribute__((ext_vector_type(8))) short bf16x8;
typedef __attribute__((ext_vector_type(4))) int i32x4;
typedef __hip_bfloat16 bf16;

__device__ inline void gload_lds16(const void* g, void* l) {
  __builtin_amdgcn_global_load_lds(
      (const __attribute__((address_space(1))) void*)g,
      (__attribute__((address_space(3))) void*)l, 16, 0, 0);
}

__device__ inline bf16x8 as_bf16x8(i32x4 x) {
  union { i32x4 i; bf16x8 v; } u; u.i = x; return u.v;
}
__device__ inline int cvt_pk_bf16(float lo, float hi) {
  int r;
  asm("v_cvt_pk_bf16_f32 %0, %1, %2" : "=v"(r) : "v"(lo), "v"(hi));
  return r;
}

// ---------------- fused fp32 -> bf16 conversion (all 5 inputs) ----------------
__global__ __launch_bounds__(256) void cvt_all(
    const float* __restrict__ q, const float* __restrict__ c,
    const float* __restrict__ wq, const float* __restrict__ wkv,
    const float* __restrict__ wo,
    bf16* __restrict__ oq, bf16* __restrict__ oc, bf16* __restrict__ owq,
    bf16* __restrict__ owkv, bf16* __restrict__ owo) {
  const int N0 = 1048576, N1 = 1048576, N2 = 262144, N3 = 524288, N4 = 262144;
  const int total = N0 + N1 + N2 + N3 + N4;
  for (int i = blockIdx.x * 256 + threadIdx.x; i < total; i += gridDim.x * 256) {
    const float* src; bf16* dst; int off = i;
    if (i < N0)                { src = q;   dst = oq; }
    else if (i < N0 + N1)      { src = c;   dst = oc;   off -= N0; }
    else if (i < N0 + N1 + N2) { src = wq;  dst = owq;  off -= N0 + N1; }
    else if (i < N0 + N1 + N2 + N3) { src = wkv; dst = owkv; off -= N0 + N1 + N2; }
    else                       { src = wo;  dst = owo;  off -= N0 + N1 + N2 + N3; }
    float4 v = ((const float4*)src)[off];
    bf16 b0 = __float2bfloat16(v.x), b1 = __float2bfloat16(v.y);
    bf16 b2 = __float2bfloat16(v.z), b3 = __float2bfloat16(v.w);
    ushort4 o;
    o.x = *(unsigned short*)&b0; o.y = *(unsigned short*)&b1;
    o.z = *(unsigned short*)&b2; o.w = *(unsigned short*)&b3;
    ((ushort4*)dst)[off] = o;
  }
}

// ---------------- GEMM: C[M,N] = alpha * A[M,K] * B[N,K]^T (m97 structure) ----------------
__device__ inline void storeC(float* C, size_t i, float v) { C[i] = v; }
__device__ inline void storeC(bf16* C, size_t i, float v)  { C[i] = __float2bfloat16(v); }

template <typename OutT>
__global__ __launch_bounds__(256) void gemm_bt(
    const bf16* __restrict__ A, const bf16* __restrict__ B,
    OutT* __restrict__ C, int M, int N, int K, float alpha) {
  __shared__ __align__(16) bf16 Als[128 * 32];
  __shared__ __align__(16) bf16 Bls[128 * 32];
  const int tid = threadIdx.x;
  const int lane = tid & 63, wid = tid >> 6;
  const int wr = wid >> 1, wc = wid & 1;
  const int bm = blockIdx.y * 128, bn = blockIdx.x * 128;
  const int fr = lane & 15, fq = lane >> 4;

  f32x4 acc[4][4] = {};

  const int kTiles = K >> 5;
  for (int kt = 0; kt < kTiles; ++kt) {
    const int k0 = kt << 5;
    __syncthreads();
#pragma unroll
    for (int j = 0; j < 2; ++j) {
      int ob = wid * 2048 + j * 1024;
      int o = ob + lane * 16;
      int r = o >> 6;
      int kk = (o & 63) >> 1;
      gload_lds16(A + (size_t)(bm + r) * K + k0 + kk, (char*)Als + ob);
      gload_lds16(B + (size_t)(bn + r) * K + k0 + kk, (char*)Bls + ob);
    }
    __syncthreads();
    bf16x8 af[4], bfr[4];
#pragma unroll
    for (int m = 0; m < 4; ++m)
      af[m] = *(const bf16x8*)(Als + (wr * 64 + m * 16 + fr) * 32 + fq * 8);
#pragma unroll
    for (int n = 0; n < 4; ++n)
      bfr[n] = *(const bf16x8*)(Bls + (wc * 64 + n * 16 + fr) * 32 + fq * 8);
#pragma unroll
    for (int m = 0; m < 4; ++m)
#pragma unroll
      for (int n = 0; n < 4; ++n)
        acc[m][n] = __builtin_amdgcn_mfma_f32_16x16x32_bf16(af[m], bfr[n], acc[m][n], 0, 0, 0);
  }
#pragma unroll
  for (int m = 0; m < 4; ++m)
#pragma unroll
    for (int n = 0; n < 4; ++n)
#pragma unroll
      for (int i = 0; i < 4; ++i) {
        int row = bm + wr * 64 + m * 16 + fq * 4 + i;
        int col = bn + wc * 64 + n * 16 + fr;
        storeC(C, (size_t)row * N + col, acc[m][n][i] * alpha);
      }
}

// ---------------- V transpose: Vt[b][h][a][s] = KV[b*S+s][DIM + h*HD + a] ----------------
__global__ __launch_bounds__(256) void transpose_v(
    const bf16* __restrict__ KV, bf16* __restrict__ Vt) {
  __shared__ __align__(16) bf16 tile[64][72];
  const int t = threadIdx.x;
  const int s0 = blockIdx.x * 64, h = blockIdx.y, b = blockIdx.z;
#pragma unroll
  for (int j = 0; j < 2; ++j) {
    int s = j * 32 + (t >> 3);
    int a = (t & 7) * 8;
    bf16x8 v = *(const bf16x8*)(KV + (size_t)(b * S_LEN + s0 + s) * (2 * DIM) + DIM + h * HD + a);
    *(bf16x8*)&tile[s][a] = v;
  }
  __syncthreads();
#pragma unroll
  for (int j = 0; j < 2; ++j) {
    int a = j * 32 + (t >> 3);
    int sc = (t & 7) * 8;
    bf16x8 v;
#pragma unroll
    for (int e = 0; e < 8; ++e)
      ((short*)&v)[e] = *(const short*)&tile[sc + e][a];
    *(bf16x8*)(Vt + (size_t)((b * NH + h) * HD + a) * S_LEN + s0 + sc) = v;
  }
}

// ---------------- Flash attention: swapped QK^T, 32x32 MFMA, in-register P ----------------
// grid: (S/128, NH, BATCH) heavy-first; 256 threads = 4 waves; wave = 32 q rows (q = lane&31).
// Q pre-scaled by log2(e)/sqrt(D); P = exp2(S); per-lane row sums, reduced once at end.
__global__ __launch_bounds__(256, 4) void attn_fwd(
    const bf16* __restrict__ Q,   // [B*S][DIM] (pre-scaled)
    const bf16* __restrict__ KV,  // [B*S][2*DIM] (K = first DIM cols)
    const bf16* __restrict__ Vt,  // [B*NH][HD][S]
    bf16* __restrict__ O) {       // [B*S][DIM]
  __shared__ __align__(16) bf16 Kls[2][64 * 64];  // [key][a], 128B rows, xor-swizzled
  __shared__ __align__(16) bf16 Vls[2][64 * 64];  // [a][key], 128B rows, xor-swizzled
  __shared__ float Rls[128];                      // per-block 1/rowsum
  const int tid = threadIdx.x, lane = tid & 63, wid = tid >> 6;
  const int l31 = lane & 31, hi = lane >> 5;
  const int qx = (int)gridDim.x - 1 - blockIdx.x;  // heavy tiles first
  const int h = blockIdx.y, b = blockIdx.z;
  const int rw0 = qx * 128 + wid * 32;
  const int qrow = rw0 + l31;                      // this lane's q row
  const float NEGINF = -__builtin_inff();

  // Q B-fragments (col = q = lane&31, k = a): 4 a-blocks of 16
  bf16x8 qf[4];
#pragma unroll
  for (int ka = 0; ka < 4; ++ka)
    qf[ka] = *(const bf16x8*)(Q + (size_t)(b * S_LEN + qrow) * DIM + h * HD + ka * 16 + hi * 8);

  f32x16 oacc[2] = {};
  float rsum = 0.f;

  auto stage = [&](int buf, int kt) {
#pragma unroll
    for (int j = 0; j < 2; ++j) {
      int ob = (wid * 2 + j) * 1024;
      int o = ob + lane * 16;
      int r = o >> 7;                       // row (key for K, a for V)
      int sb = (o & 127) ^ ((r & 7) << 4);  // pre-swizzled byte within row
      gload_lds16(KV + (size_t)(b * S_LEN + kt * 64 + r) * (2 * DIM) + h * HD + (sb >> 1),
                  (char*)Kls[buf] + ob);
      gload_lds16(Vt + (size_t)((b * NH + h) * HD + r) * S_LEN + kt * 64 + (sb >> 1),
                  (char*)Vls[buf] + ob);
    }
  };

  const int nt = 2 * qx + 2;  // causal bound in 64-key tiles
  int cur = 0;
  stage(0, 0);
  asm volatile("s_waitcnt vmcnt(0)" ::: "memory");
  __syncthreads();

  for (int kt = 0; kt < nt; ++kt) {
    if (kt + 1 < nt) stage(cur ^ 1, kt + 1);  // async prefetch under compute

    if (64 * kt <= rw0 + 31) {  // skip fully-masked tiles for this wave
      const bf16* Kb = Kls[cur];
      const bf16* Vb = Vls[cur];
      const bool maskt = (64 * kt + 63 > rw0);

#pragma unroll
      for (int kb = 0; kb < 2; ++kb) {
        // ---- S^T = K Q^T over this 32-key block ----
        f32x16 c = {};
        __builtin_amdgcn_s_setprio(1);
#pragma unroll
        for (int ka = 0; ka < 4; ++ka) {
          int row = kb * 32 + l31;
          bf16x8 kf = *(const bf16x8*)((const char*)Kb + row * 128 +
                                       ((ka * 32 + hi * 16) ^ ((row & 7) << 4)));
          c = __builtin_amdgcn_mfma_f32_32x32x16_bf16(kf, qf[ka], c, 0, 0, 0);
        }
        __builtin_amdgcn_s_setprio(0);

        // ---- P = exp2(S) in-register; per-lane row-sum ----
        float pe[16];
        if (maskt) {
#pragma unroll
          for (int r = 0; r < 16; ++r) {
            int key = kt * 64 + kb * 32 + (r & 3) + 8 * (r >> 2) + 4 * hi;
            float s = (key <= qrow) ? c[r] : NEGINF;
            pe[r] = __builtin_amdgcn_exp2f(s);
            rsum += pe[r];
          }
        } else {
#pragma unroll
          for (int r = 0; r < 16; ++r) {
            pe[r] = __builtin_amdgcn_exp2f(c[r]);
            rsum += pe[r];
          }
        }

        // ---- pack to bf16 pairs; exchange across half-waves; build PV A-frags ----
        int u[8], x[8];
#pragma unroll
        for (int t = 0; t < 8; ++t) u[t] = cvt_pk_bf16(pe[2 * t], pe[2 * t + 1]);
#pragma unroll
        for (int t = 0; t < 8; ++t) x[t] = __shfl_xor(u[t], 32);
        i32x4 w0, w1;
        w0[0] = hi ? x[2] : u[0]; w0[1] = hi ? x[3] : u[1];
        w0[2] = hi ? u[2] : x[0]; w0[3] = hi ? u[3] : x[1];
        w1[0] = hi ? x[6] : u[4]; w1[1] = hi ? x[7] : u[5];
        w1[2] = hi ? u[6] : x[4]; w1[3] = hi ? u[7] : x[5];
        bf16x8 pa0 = as_bf16x8(w0), pa1 = as_bf16x8(w1);

        // ---- PV: O += P * V ----
        __builtin_amdgcn_s_setprio(1);
#pragma unroll
        for (int pl = 0; pl < 2; ++pl) {
          bf16x8 pa = pl ? pa1 : pa0;
#pragma unroll
          for (int nb = 0; nb < 2; ++nb) {
            int a = nb * 32 + l31;
            bf16x8 vf = *(const bf16x8*)((const char*)Vb + a * 128 +
                                         ((kb * 64 + pl * 32 + hi * 16) ^ ((a & 7) << 4)));
            oacc[nb] = __builtin_amdgcn_mfma_f32_32x32x16_bf16(pa, vf, oacc[nb], 0, 0, 0);
          }
        }
        __builtin_amdgcn_s_setprio(0);
      }
    }

    asm volatile("s_waitcnt vmcnt(0)" ::: "memory");  // prefetch landed
    __syncthreads();
    cur ^= 1;
  }

  // ---- finalize: cross-half row-sum, broadcast 1/sum via LDS, store ----
  rsum += __shfl_xor(rsum, 32);
  if (hi == 0) Rls[wid * 32 + l31] = 1.0f / rsum;
#pragma unroll
  for (int nb = 0; nb < 2; ++nb)
#pragma unroll
    for (int r = 0; r < 16; ++r) {
      int qloc = (r & 3) + 8 * (r >> 2) + 4 * hi;
      float rv = Rls[wid * 32 + qloc];
      int qg = rw0 + qloc;
      O[(size_t)(b * S_LEN + qg) * DIM + h * HD + nb * 32 + l31] =
          __float2bfloat16(oacc[nb][r] * rv);
    }
}

// ---------------- launch ----------------
extern "C" void kernel_launch(void* const* d_in, const int* in_sizes, int n_in,
                              void* d_out, int out_size, void* d_ws, size_t ws_size,
                              hipStream_t stream) {
  (void)in_sizes; (void)n_in; (void)out_size; (void)ws_size;
  const float* query   = (const float*)d_in[0];  // [B,S,D]
  const float* context = (const float*)d_in[1];  // [B,S,D]
  const float* Wq      = (const float*)d_in[2];  // [D,D]
  const float* Wkv     = (const float*)d_in[3];  // [2D,D]
  const float* Wout    = (const float*)d_in[4];  // [D,D]
  float* out = (float*)d_out;

  bf16* ws = (bf16*)d_ws;
  const size_t nBSD = (size_t)BATCH * S_LEN * DIM;  // 4194304
  bf16* qbf    = ws;
  bf16* cbf    = qbf + nBSD;
  bf16* wqbf   = cbf + nBSD;
  bf16* wkvbf  = wqbf + (size_t)DIM * DIM;
  bf16* woutbf = wkvbf + (size_t)2 * DIM * DIM;
  bf16* Qp     = woutbf + (size_t)DIM * DIM;
  bf16* KVp    = Qp + nBSD;
  bf16* Vtp    = KVp + 2 * nBSD;
  bf16* Op     = Vtp + nBSD;

  // fused conversions (one launch)
  cvt_all<<<2048, 256, 0, stream>>>(query, context, Wq, Wkv, Wout,
                                    qbf, cbf, wqbf, wkvbf, woutbf);

  const int M = BATCH * S_LEN;  // 4096
  // Q = (query * Wq^T) * (log2(e)/sqrt(D))
  gemm_bt<bf16><<<dim3(DIM / 128, M / 128), 256, 0, stream>>>(qbf, wqbf, Qp, M, DIM, DIM,
                                                              0.0450842200277801f);
  // KV = context * Wkv^T
  gemm_bt<bf16><<<dim3(2 * DIM / 128, M / 128), 256, 0, stream>>>(cbf, wkvbf, KVp, M, 2 * DIM, DIM, 1.0f);
  // Vt
  transpose_v<<<dim3(S_LEN / 64, NH, BATCH), 256, 0, stream>>>(KVp, Vtp);
  // attention
  attn_fwd<<<dim3(S_LEN / 128, NH, BATCH), 256, 0, stream>>>(Qp, KVp, Vtp, Op);
  // out = O * Wout^T
  gemm_bt<float><<<dim3(DIM / 128, M / 128), 256, 0, stream>>>(Op, woutbf, out, M, DIM, DIM, 1.0f);
}

// Round 5
// 126.941 us; speedup vs baseline: 2.1167x; 1.2352x over previous
//
#include <hip/hip_runtime.h>
#include <hip/hip_bf16.h>
#include <stdint.h>

#define S_LEN 2048
#define DIM   1024
#define NH    16
#define HD    64
#define BATCH 2

typedef __attribute__((ext_vector_type(4))) float f32x4;
typedef __attribute__((ext_vector_type(16))) float f32x16;
typedef __attribute__((ext_vector_type(8))) short bf16x8;
typedef __attribute__((ext_vector_type(4))) int i32x4;
typedef __hip_bfloat16 bf16;

__device__ inline void gload_lds16(const void* g, void* l) {
  __builtin_amdgcn_global_load_lds(
      (const __attribute__((address_space(1))) void*)g,
      (__attribute__((address_space(3))) void*)l, 16, 0, 0);
}

__device__ inline bf16x8 as_bf16x8(i32x4 x) {
  union { i32x4 i; bf16x8 v; } u; u.i = x; return u.v;
}
__device__ inline int cvt_pk_bf16(float lo, float hi) {
  int r;
  asm("v_cvt_pk_bf16_f32 %0, %1, %2" : "=v"(r) : "v"(lo), "v"(hi));
  return r;
}

// ---------------- fused fp32 -> bf16 conversion (all 5 inputs) ----------------
__global__ __launch_bounds__(256) void cvt_all(
    const float* __restrict__ q, const float* __restrict__ c,
    const float* __restrict__ wq, const float* __restrict__ wkv,
    const float* __restrict__ wo,
    bf16* __restrict__ oq, bf16* __restrict__ oc, bf16* __restrict__ owq,
    bf16* __restrict__ owkv, bf16* __restrict__ owo) {
  const int N0 = 1048576, N1 = 1048576, N2 = 262144, N3 = 524288, N4 = 262144;
  const int total = N0 + N1 + N2 + N3 + N4;
  for (int i = blockIdx.x * 256 + threadIdx.x; i < total; i += gridDim.x * 256) {
    const float* src; bf16* dst; int off = i;
    if (i < N0)                { src = q;   dst = oq; }
    else if (i < N0 + N1)      { src = c;   dst = oc;   off -= N0; }
    else if (i < N0 + N1 + N2) { src = wq;  dst = owq;  off -= N0 + N1; }
    else if (i < N0 + N1 + N2 + N3) { src = wkv; dst = owkv; off -= N0 + N1 + N2; }
    else                       { src = wo;  dst = owo;  off -= N0 + N1 + N2 + N3; }
    float4 v = ((const float4*)src)[off];
    bf16 b0 = __float2bfloat16(v.x), b1 = __float2bfloat16(v.y);
    bf16 b2 = __float2bfloat16(v.z), b3 = __float2bfloat16(v.w);
    ushort4 o;
    o.x = *(unsigned short*)&b0; o.y = *(unsigned short*)&b1;
    o.z = *(unsigned short*)&b2; o.w = *(unsigned short*)&b3;
    ((ushort4*)dst)[off] = o;
  }
}

// ---------------- grouped GEMM core: C[.,N] = alpha*A[.,K]*B[N,K]^T, 128x128 ----------------
__device__ inline void gemm128_body(const bf16* __restrict__ A, const bf16* __restrict__ B,
                                    bf16* __restrict__ C, int N, int K, float alpha,
                                    int bm, int bn, bf16* Als, bf16* Bls) {
  const int tid = threadIdx.x;
  const int lane = tid & 63, wid = tid >> 6;
  const int wr = wid >> 1, wc = wid & 1;
  const int fr = lane & 15, fq = lane >> 4;

  f32x4 acc[4][4] = {};
  const int kTiles = K >> 5;
  for (int kt = 0; kt < kTiles; ++kt) {
    const int k0 = kt << 5;
    __syncthreads();
#pragma unroll
    for (int j = 0; j < 2; ++j) {
      int ob = wid * 2048 + j * 1024;
      int o = ob + lane * 16;
      int r = o >> 6;
      int kk = (o & 63) >> 1;
      gload_lds16(A + (size_t)(bm + r) * K + k0 + kk, (char*)Als + ob);
      gload_lds16(B + (size_t)(bn + r) * K + k0 + kk, (char*)Bls + ob);
    }
    __syncthreads();
    bf16x8 af[4], bfr[4];
#pragma unroll
    for (int m = 0; m < 4; ++m)
      af[m] = *(const bf16x8*)(Als + (wr * 64 + m * 16 + fr) * 32 + fq * 8);
#pragma unroll
    for (int n = 0; n < 4; ++n)
      bfr[n] = *(const bf16x8*)(Bls + (wc * 64 + n * 16 + fr) * 32 + fq * 8);
#pragma unroll
    for (int m = 0; m < 4; ++m)
#pragma unroll
      for (int n = 0; n < 4; ++n)
        acc[m][n] = __builtin_amdgcn_mfma_f32_16x16x32_bf16(af[m], bfr[n], acc[m][n], 0, 0, 0);
  }
#pragma unroll
  for (int m = 0; m < 4; ++m)
#pragma unroll
    for (int n = 0; n < 4; ++n)
#pragma unroll
      for (int i = 0; i < 4; ++i) {
        int row = bm + wr * 64 + m * 16 + fq * 4 + i;
        int col = bn + wc * 64 + n * 16 + fr;
        C[(size_t)row * N + col] = __float2bfloat16(acc[m][n][i] * alpha);
      }
}

// Q-proj (256 blocks) + KV-proj (512 blocks) grouped into one 768-block dispatch.
__global__ __launch_bounds__(256) void gemm_proj(
    const bf16* __restrict__ Aq, const bf16* __restrict__ Bq, bf16* __restrict__ Cq,
    const bf16* __restrict__ Akv, const bf16* __restrict__ Bkv, bf16* __restrict__ Ckv,
    float qalpha) {
  __shared__ __align__(16) bf16 Als[128 * 32];
  __shared__ __align__(16) bf16 Bls[128 * 32];
  const int bid = blockIdx.x;
  const bf16 *A, *B; bf16 *C; int N; float alpha; int bx, by;
  if (bid < 256) { A = Aq;  B = Bq;  C = Cq;  N = 1024; alpha = qalpha; bx = bid & 7;  by = bid >> 3; }
  else { int t = bid - 256; A = Akv; B = Bkv; C = Ckv; N = 2048; alpha = 1.0f; bx = t & 15; by = t >> 4; }
  gemm128_body(A, B, C, N, 1024, alpha, by * 128, bx * 128, Als, Bls);
}

// ---------------- out-proj GEMM: BM=128, BN=64 -> 512 blocks (fp32 out) ----------------
__global__ __launch_bounds__(256) void gemm_bt_n64(
    const bf16* __restrict__ A, const bf16* __restrict__ B,
    float* __restrict__ C, int M, int N, int K) {
  __shared__ __align__(16) bf16 Als[128 * 32];
  __shared__ __align__(16) bf16 Bls[64 * 32];
  const int tid = threadIdx.x;
  const int lane = tid & 63, wid = tid >> 6;
  const int bm = blockIdx.y * 128, bn = blockIdx.x * 64;
  const int fr = lane & 15, fq = lane >> 4;

  f32x4 acc[2][4] = {};
  const int kTiles = K >> 5;
  for (int kt = 0; kt < kTiles; ++kt) {
    const int k0 = kt << 5;
    __syncthreads();
#pragma unroll
    for (int j = 0; j < 2; ++j) {
      int ob = wid * 2048 + j * 1024;
      int o = ob + lane * 16;
      int r = o >> 6;
      int kk = (o & 63) >> 1;
      gload_lds16(A + (size_t)(bm + r) * K + k0 + kk, (char*)Als + ob);
    }
    {
      int ob = wid * 1024;
      int o = ob + lane * 16;
      int r = o >> 6;
      int kk = (o & 63) >> 1;
      gload_lds16(B + (size_t)(bn + r) * K + k0 + kk, (char*)Bls + ob);
    }
    __syncthreads();
    bf16x8 af[2], bfr[4];
#pragma unroll
    for (int m = 0; m < 2; ++m)
      af[m] = *(const bf16x8*)(Als + (wid * 32 + m * 16 + fr) * 32 + fq * 8);
#pragma unroll
    for (int n = 0; n < 4; ++n)
      bfr[n] = *(const bf16x8*)(Bls + (n * 16 + fr) * 32 + fq * 8);
#pragma unroll
    for (int m = 0; m < 2; ++m)
#pragma unroll
      for (int n = 0; n < 4; ++n)
        acc[m][n] = __builtin_amdgcn_mfma_f32_16x16x32_bf16(af[m], bfr[n], acc[m][n], 0, 0, 0);
  }
#pragma unroll
  for (int m = 0; m < 2; ++m)
#pragma unroll
    for (int n = 0; n < 4; ++n)
#pragma unroll
      for (int i = 0; i < 4; ++i) {
        int row = bm + wid * 32 + m * 16 + fq * 4 + i;
        int col = bn + n * 16 + fr;
        C[(size_t)row * N + col] = acc[m][n][i];
      }
}

// ---------------- V transpose: Vt[b][h][a][s] = KV[b*S+s][DIM + h*HD + a] ----------------
__global__ __launch_bounds__(256) void transpose_v(
    const bf16* __restrict__ KV, bf16* __restrict__ Vt) {
  __shared__ __align__(16) bf16 tile[64][72];
  const int t = threadIdx.x;
  const int s0 = blockIdx.x * 64, h = blockIdx.y, b = blockIdx.z;
#pragma unroll
  for (int j = 0; j < 2; ++j) {
    int s = j * 32 + (t >> 3);
    int a = (t & 7) * 8;
    bf16x8 v = *(const bf16x8*)(KV + (size_t)(b * S_LEN + s0 + s) * (2 * DIM) + DIM + h * HD + a);
    *(bf16x8*)&tile[s][a] = v;
  }
  __syncthreads();
#pragma unroll
  for (int j = 0; j < 2; ++j) {
    int a = j * 32 + (t >> 3);
    int sc = (t & 7) * 8;
    bf16x8 v;
#pragma unroll
    for (int e = 0; e < 8; ++e)
      ((short*)&v)[e] = *(const short*)&tile[sc + e][a];
    *(bf16x8*)(Vt + (size_t)((b * NH + h) * HD + a) * S_LEN + s0 + sc) = v;
  }
}

// ---------------- Flash attention: swapped QK^T, 32x32 MFMA, in-register P ----------------
// 1D grid of 512, globally heavy-first; 256 threads = 4 waves; wave = 32 q rows.
// Triple-buffered K/V staging with counted vmcnt (no drain in main loop).
__global__ __launch_bounds__(256, 4) void attn_fwd(
    const bf16* __restrict__ Q,   // [B*S][DIM] (pre-scaled by log2e/sqrt(D))
    const bf16* __restrict__ KV,  // [B*S][2*DIM] (K = first DIM cols)
    const bf16* __restrict__ Vt,  // [B*NH][HD][S]
    bf16* __restrict__ O) {       // [B*S][DIM]
  __shared__ __align__(16) bf16 Kls[3][64 * 64];  // [key][a], 128B rows, xor-swizzled
  __shared__ __align__(16) bf16 Vls[3][64 * 64];  // [a][key], 128B rows, xor-swizzled
  __shared__ float Rls[128];
  const int tid = threadIdx.x, lane = tid & 63, wid = tid >> 6;
  const int l31 = lane & 31, hi = lane >> 5;
  const int bid = blockIdx.x;
  const int qx = 15 - (bid >> 5);           // all heavy blocks dispatch first
  const int hb = bid & 31;
  const int h = hb >> 1, b = hb & 1;
  const int rw0 = qx * 128 + wid * 32;
  const int qrow = rw0 + l31;
  const float NEGINF = -__builtin_inff();

  // Q B-fragments (col = q = lane&31): 4 a-blocks of 16
  bf16x8 qf[4];
#pragma unroll
  for (int ka = 0; ka < 4; ++ka)
    qf[ka] = *(const bf16x8*)(Q + (size_t)(b * S_LEN + qrow) * DIM + h * HD + ka * 16 + hi * 8);

  f32x16 oacc[2] = {};
  float rsum = 0.f;

  auto stage = [&](int buf, int kt) {
#pragma unroll
    for (int j = 0; j < 2; ++j) {
      int ob = (wid * 2 + j) * 1024;
      int o = ob + lane * 16;
      int r = o >> 7;
      int sb = (o & 127) ^ ((r & 7) << 4);
      gload_lds16(KV + (size_t)(b * S_LEN + kt * 64 + r) * (2 * DIM) + h * HD + (sb >> 1),
                  (char*)Kls[buf] + ob);
      gload_lds16(Vt + (size_t)((b * NH + h) * HD + r) * S_LEN + kt * 64 + (sb >> 1),
                  (char*)Vls[buf] + ob);
    }
  };

  const int nt = 2 * qx + 2;  // causal bound in 64-key tiles (>= 2)
  stage(0, 0);
  stage(1, 1 < nt ? 1 : 0);   // nt>=2 always; kept safe

  for (int kt = 0; kt < nt; ++kt) {
    // tile kt landed (own 4 loads); tile kt+1 may stay in flight across the barrier
    if (kt + 1 < nt) asm volatile("s_waitcnt vmcnt(4)" ::: "memory");
    else             asm volatile("s_waitcnt vmcnt(0)" ::: "memory");
    __syncthreads();

    const int cb = kt % 3;
    if (64 * kt <= rw0 + 31) {  // skip fully-masked tiles for this wave
      const bf16* Kb = Kls[cb];
      const bf16* Vb = Vls[cb];
      const bool maskt = (64 * kt + 63 > rw0);

#pragma unroll
      for (int kb = 0; kb < 2; ++kb) {
        // ---- S^T = K Q^T over this 32-key block ----
        f32x16 c = {};
        __builtin_amdgcn_s_setprio(1);
#pragma unroll
        for (int ka = 0; ka < 4; ++ka) {
          int row = kb * 32 + l31;
          bf16x8 kf = *(const bf16x8*)((const char*)Kb + row * 128 +
                                       ((ka * 32 + hi * 16) ^ ((row & 7) << 4)));
          c = __builtin_amdgcn_mfma_f32_32x32x16_bf16(kf, qf[ka], c, 0, 0, 0);
        }
        __builtin_amdgcn_s_setprio(0);

        // ---- P = exp2(S); per-lane row-sum ----
        float pe[16];
        if (maskt) {
#pragma unroll
          for (int r = 0; r < 16; ++r) {
            int key = kt * 64 + kb * 32 + (r & 3) + 8 * (r >> 2) + 4 * hi;
            float s = (key <= qrow) ? c[r] : NEGINF;
            pe[r] = __builtin_amdgcn_exp2f(s);
            rsum += pe[r];
          }
        } else {
#pragma unroll
          for (int r = 0; r < 16; ++r) {
            pe[r] = __builtin_amdgcn_exp2f(c[r]);
            rsum += pe[r];
          }
        }

        // ---- pack to bf16; half-wave exchange; PV A-frags in registers ----
        int u[8], x[8];
#pragma unroll
        for (int t = 0; t < 8; ++t) u[t] = cvt_pk_bf16(pe[2 * t], pe[2 * t + 1]);
#pragma unroll
        for (int t = 0; t < 8; ++t) x[t] = __shfl_xor(u[t], 32);
        i32x4 w0, w1;
        w0[0] = hi ? x[2] : u[0]; w0[1] = hi ? x[3] : u[1];
        w0[2] = hi ? u[2] : x[0]; w0[3] = hi ? u[3] : x[1];
        w1[0] = hi ? x[6] : u[4]; w1[1] = hi ? x[7] : u[5];
        w1[2] = hi ? u[6] : x[4]; w1[3] = hi ? u[7] : x[5];
        bf16x8 pa0 = as_bf16x8(w0), pa1 = as_bf16x8(w1);

        // ---- PV: O += P * V ----
        __builtin_amdgcn_s_setprio(1);
#pragma unroll
        for (int pl = 0; pl < 2; ++pl) {
          bf16x8 pa = pl ? pa1 : pa0;
#pragma unroll
          for (int nb = 0; nb < 2; ++nb) {
            int a = nb * 32 + l31;
            bf16x8 vf = *(const bf16x8*)((const char*)Vb + a * 128 +
                                         ((kb * 64 + pl * 32 + hi * 16) ^ ((a & 7) << 4)));
            oacc[nb] = __builtin_amdgcn_mfma_f32_32x32x16_bf16(pa, vf, oacc[nb], 0, 0, 0);
          }
        }
        __builtin_amdgcn_s_setprio(0);
      }
    }

    if (kt + 2 < nt) stage((kt + 2) % 3, kt + 2);  // safe: buf (kt+2)%3 != kt%3, (kt+1)%3
  }

  // ---- finalize ----
  rsum += __shfl_xor(rsum, 32);
  if (hi == 0) Rls[wid * 32 + l31] = 1.0f / rsum;
#pragma unroll
  for (int nb = 0; nb < 2; ++nb)
#pragma unroll
    for (int r = 0; r < 16; ++r) {
      int qloc = (r & 3) + 8 * (r >> 2) + 4 * hi;
      float rv = Rls[wid * 32 + qloc];
      int qg = rw0 + qloc;
      O[(size_t)(b * S_LEN + qg) * DIM + h * HD + nb * 32 + l31] =
          __float2bfloat16(oacc[nb][r] * rv);
    }
}

// ---------------- launch ----------------
extern "C" void kernel_launch(void* const* d_in, const int* in_sizes, int n_in,
                              void* d_out, int out_size, void* d_ws, size_t ws_size,
                              hipStream_t stream) {
  (void)in_sizes; (void)n_in; (void)out_size; (void)ws_size;
  const float* query   = (const float*)d_in[0];
  const float* context = (const float*)d_in[1];
  const float* Wq      = (const float*)d_in[2];
  const float* Wkv     = (const float*)d_in[3];
  const float* Wout    = (const float*)d_in[4];
  float* out = (float*)d_out;

  bf16* ws = (bf16*)d_ws;
  const size_t nBSD = (size_t)BATCH * S_LEN * DIM;  // 4194304
  bf16* qbf    = ws;
  bf16* cbf    = qbf + nBSD;
  bf16* wqbf   = cbf + nBSD;
  bf16* wkvbf  = wqbf + (size_t)DIM * DIM;
  bf16* woutbf = wkvbf + (size_t)2 * DIM * DIM;
  bf16* Qp     = woutbf + (size_t)DIM * DIM;
  bf16* KVp    = Qp + nBSD;
  bf16* Vtp    = KVp + 2 * nBSD;
  bf16* Op     = Vtp + nBSD;

  // fused conversions
  cvt_all<<<2048, 256, 0, stream>>>(query, context, Wq, Wkv, Wout,
                                    qbf, cbf, wqbf, wkvbf, woutbf);

  // Q-proj (scaled by log2e/sqrt(D)) + KV-proj grouped: 768 blocks, ~3/CU
  gemm_proj<<<768, 256, 0, stream>>>(qbf, wqbf, Qp, cbf, wkvbf, KVp, 0.0450842200277801f);

  // Vt
  transpose_v<<<dim3(S_LEN / 64, NH, BATCH), 256, 0, stream>>>(KVp, Vtp);
  // attention: 1D heavy-first grid
  attn_fwd<<<512, 256, 0, stream>>>(Qp, KVp, Vtp, Op);
  // out = O * Wout^T  (BN=64 -> 512 blocks)
  const int M = BATCH * S_LEN;
  gemm_bt_n64<<<dim3(DIM / 64, M / 128), 256, 0, stream>>>(Op, woutbf, out, M, DIM, DIM);
}

// Round 6
// 120.428 us; speedup vs baseline: 2.2311x; 1.0541x over previous
//
#include <hip/hip_runtime.h>
#include <hip/hip_bf16.h>
#include <stdint.h>

#define S_LEN 2048
#define DIM   1024
#define NH    16
#define HD    64
#define BATCH 2

typedef __attribute__((ext_vector_type(4))) float f32x4;
typedef __attribute__((ext_vector_type(16))) float f32x16;
typedef __attribute__((ext_vector_type(8))) short bf16x8;
typedef __attribute__((ext_vector_type(4))) int i32x4;
typedef __hip_bfloat16 bf16;

__device__ inline void gload_lds16(const void* g, void* l) {
  __builtin_amdgcn_global_load_lds(
      (const __attribute__((address_space(1))) void*)g,
      (__attribute__((address_space(3))) void*)l, 16, 0, 0);
}

__device__ inline bf16x8 as_bf16x8(i32x4 x) {
  union { i32x4 i; bf16x8 v; } u; u.i = x; return u.v;
}
__device__ inline int cvt_pk_bf16(float lo, float hi) {
  int r;
  asm("v_cvt_pk_bf16_f32 %0, %1, %2" : "=v"(r) : "v"(lo), "v"(hi));
  return r;
}
__device__ inline float b2f(short s) {
  union { unsigned int u; float f; } w;
  w.u = ((unsigned int)(unsigned short)s) << 16;
  return w.f;
}

// ---------------- fused fp32 -> bf16 conversion (all 5 inputs) ----------------
__global__ __launch_bounds__(256) void cvt_all(
    const float* __restrict__ q, const float* __restrict__ c,
    const float* __restrict__ wq, const float* __restrict__ wkv,
    const float* __restrict__ wo,
    bf16* __restrict__ oq, bf16* __restrict__ oc, bf16* __restrict__ owq,
    bf16* __restrict__ owkv, bf16* __restrict__ owo) {
  const int N0 = 1048576, N1 = 1048576, N2 = 262144, N3 = 524288, N4 = 262144;
  const int total = N0 + N1 + N2 + N3 + N4;
  for (int i = blockIdx.x * 256 + threadIdx.x; i < total; i += gridDim.x * 256) {
    const float* src; bf16* dst; int off = i;
    if (i < N0)                { src = q;   dst = oq; }
    else if (i < N0 + N1)      { src = c;   dst = oc;   off -= N0; }
    else if (i < N0 + N1 + N2) { src = wq;  dst = owq;  off -= N0 + N1; }
    else if (i < N0 + N1 + N2 + N3) { src = wkv; dst = owkv; off -= N0 + N1 + N2; }
    else                       { src = wo;  dst = owo;  off -= N0 + N1 + N2 + N3; }
    float4 v = ((const float4*)src)[off];
    bf16 b0 = __float2bfloat16(v.x), b1 = __float2bfloat16(v.y);
    bf16 b2 = __float2bfloat16(v.z), b3 = __float2bfloat16(v.w);
    ushort4 o;
    o.x = *(unsigned short*)&b0; o.y = *(unsigned short*)&b1;
    o.z = *(unsigned short*)&b2; o.w = *(unsigned short*)&b3;
    ((ushort4*)dst)[off] = o;
  }
}

// ---------------- grouped GEMM core: C[.,N] = alpha*A[.,K]*B[N,K]^T, 128x128 ----------------
__device__ inline void gemm128_body(const bf16* __restrict__ A, const bf16* __restrict__ B,
                                    bf16* __restrict__ C, int N, int K, float alpha,
                                    int bm, int bn, bf16* Als, bf16* Bls) {
  const int tid = threadIdx.x;
  const int lane = tid & 63, wid = tid >> 6;
  const int wr = wid >> 1, wc = wid & 1;
  const int fr = lane & 15, fq = lane >> 4;

  f32x4 acc[4][4] = {};
  const int kTiles = K >> 5;
  for (int kt = 0; kt < kTiles; ++kt) {
    const int k0 = kt << 5;
    __syncthreads();
#pragma unroll
    for (int j = 0; j < 2; ++j) {
      int ob = wid * 2048 + j * 1024;
      int o = ob + lane * 16;
      int r = o >> 6;
      int kk = (o & 63) >> 1;
      gload_lds16(A + (size_t)(bm + r) * K + k0 + kk, (char*)Als + ob);
      gload_lds16(B + (size_t)(bn + r) * K + k0 + kk, (char*)Bls + ob);
    }
    __syncthreads();
    bf16x8 af[4], bfr[4];
#pragma unroll
    for (int m = 0; m < 4; ++m)
      af[m] = *(const bf16x8*)(Als + (wr * 64 + m * 16 + fr) * 32 + fq * 8);
#pragma unroll
    for (int n = 0; n < 4; ++n)
      bfr[n] = *(const bf16x8*)(Bls + (wc * 64 + n * 16 + fr) * 32 + fq * 8);
#pragma unroll
    for (int m = 0; m < 4; ++m)
#pragma unroll
      for (int n = 0; n < 4; ++n)
        acc[m][n] = __builtin_amdgcn_mfma_f32_16x16x32_bf16(af[m], bfr[n], acc[m][n], 0, 0, 0);
  }
#pragma unroll
  for (int m = 0; m < 4; ++m)
#pragma unroll
    for (int n = 0; n < 4; ++n)
#pragma unroll
      for (int i = 0; i < 4; ++i) {
        int row = bm + wr * 64 + m * 16 + fq * 4 + i;
        int col = bn + wc * 64 + n * 16 + fr;
        C[(size_t)row * N + col] = __float2bfloat16(acc[m][n][i] * alpha);
      }
}

// Q-proj (256 blocks) + KV-proj (512 blocks) grouped into one 768-block dispatch.
__global__ __launch_bounds__(256) void gemm_proj(
    const bf16* __restrict__ Aq, const bf16* __restrict__ Bq, bf16* __restrict__ Cq,
    const bf16* __restrict__ Akv, const bf16* __restrict__ Bkv, bf16* __restrict__ Ckv,
    float qalpha) {
  __shared__ __align__(16) bf16 Als[128 * 32];
  __shared__ __align__(16) bf16 Bls[128 * 32];
  const int bid = blockIdx.x;
  const bf16 *A, *B; bf16 *C; int N; float alpha; int bx, by;
  if (bid < 256) { A = Aq;  B = Bq;  C = Cq;  N = 1024; alpha = qalpha; bx = bid & 7;  by = bid >> 3; }
  else { int t = bid - 256; A = Akv; B = Bkv; C = Ckv; N = 2048; alpha = 1.0f; bx = t & 15; by = t >> 4; }
  gemm128_body(A, B, C, N, 1024, alpha, by * 128, bx * 128, Als, Bls);
}

// ---------------- out-proj GEMM: BM=128, BN=64 -> 512 blocks (fp32 out) ----------------
__global__ __launch_bounds__(256) void gemm_bt_n64(
    const bf16* __restrict__ A, const bf16* __restrict__ B,
    float* __restrict__ C, int M, int N, int K) {
  __shared__ __align__(16) bf16 Als[128 * 32];
  __shared__ __align__(16) bf16 Bls[64 * 32];
  const int tid = threadIdx.x;
  const int lane = tid & 63, wid = tid >> 6;
  const int bm = blockIdx.y * 128, bn = blockIdx.x * 64;
  const int fr = lane & 15, fq = lane >> 4;

  f32x4 acc[2][4] = {};
  const int kTiles = K >> 5;
  for (int kt = 0; kt < kTiles; ++kt) {
    const int k0 = kt << 5;
    __syncthreads();
#pragma unroll
    for (int j = 0; j < 2; ++j) {
      int ob = wid * 2048 + j * 1024;
      int o = ob + lane * 16;
      int r = o >> 6;
      int kk = (o & 63) >> 1;
      gload_lds16(A + (size_t)(bm + r) * K + k0 + kk, (char*)Als + ob);
    }
    {
      int ob = wid * 1024;
      int o = ob + lane * 16;
      int r = o >> 6;
      int kk = (o & 63) >> 1;
      gload_lds16(B + (size_t)(bn + r) * K + k0 + kk, (char*)Bls + ob);
    }
    __syncthreads();
    bf16x8 af[2], bfr[4];
#pragma unroll
    for (int m = 0; m < 2; ++m)
      af[m] = *(const bf16x8*)(Als + (wid * 32 + m * 16 + fr) * 32 + fq * 8);
#pragma unroll
    for (int n = 0; n < 4; ++n)
      bfr[n] = *(const bf16x8*)(Bls + (n * 16 + fr) * 32 + fq * 8);
#pragma unroll
    for (int m = 0; m < 2; ++m)
#pragma unroll
      for (int n = 0; n < 4; ++n)
        acc[m][n] = __builtin_amdgcn_mfma_f32_16x16x32_bf16(af[m], bfr[n], acc[m][n], 0, 0, 0);
  }
#pragma unroll
  for (int m = 0; m < 2; ++m)
#pragma unroll
    for (int n = 0; n < 4; ++n)
#pragma unroll
      for (int i = 0; i < 4; ++i) {
        int row = bm + wid * 32 + m * 16 + fq * 4 + i;
        int col = bn + n * 16 + fr;
        C[(size_t)row * N + col] = acc[m][n][i];
      }
}

// ---------------- V transpose: Vt[b][h][a][s] = KV[b*S+s][DIM + h*HD + a] ----------------
__global__ __launch_bounds__(256) void transpose_v(
    const bf16* __restrict__ KV, bf16* __restrict__ Vt) {
  __shared__ __align__(16) bf16 tile[64][72];
  const int t = threadIdx.x;
  const int s0 = blockIdx.x * 64, h = blockIdx.y, b = blockIdx.z;
#pragma unroll
  for (int j = 0; j < 2; ++j) {
    int s = j * 32 + (t >> 3);
    int a = (t & 7) * 8;
    bf16x8 v = *(const bf16x8*)(KV + (size_t)(b * S_LEN + s0 + s) * (2 * DIM) + DIM + h * HD + a);
    *(bf16x8*)&tile[s][a] = v;
  }
  __syncthreads();
#pragma unroll
  for (int j = 0; j < 2; ++j) {
    int a = j * 32 + (t >> 3);
    int sc = (t & 7) * 8;
    bf16x8 v;
#pragma unroll
    for (int e = 0; e < 8; ++e)
      ((short*)&v)[e] = *(const short*)&tile[sc + e][a];
    *(bf16x8*)(Vt + (size_t)((b * NH + h) * HD + a) * S_LEN + s0 + sc) = v;
  }
}

// ---------------- Flash attention, key-split x2: partial O (unnormalized) + rowsum ----------------
// 1024 blocks heavy-first: each block = one (b,h,qx,chunk); chunk = (qx+1) 64-key tiles.
// No-max softmax makes partials additive; combine kernel merges.
__global__ __launch_bounds__(256, 4) void attn_fwd(
    const bf16* __restrict__ Q,     // [B*S][DIM] (pre-scaled by log2e/sqrt(D))
    const bf16* __restrict__ KV,    // [B*S][2*DIM] (K = first DIM cols)
    const bf16* __restrict__ Vt,    // [B*NH][HD][S]
    bf16* __restrict__ Opart,       // [1024][128][64] unnormalized partial O
    float* __restrict__ Rpart) {    // [1024][128] partial row sums
  __shared__ __align__(16) bf16 Kls[3][64 * 64];  // [key][a], 128B rows, xor-swizzled
  __shared__ __align__(16) bf16 Vls[3][64 * 64];  // [a][key], 128B rows, xor-swizzled
  const int tid = threadIdx.x, lane = tid & 63, wid = tid >> 6;
  const int l31 = lane & 31, hi = lane >> 5;
  const int bid = blockIdx.x;
  const int qx = 15 - (bid >> 6);   // heavy q-blocks dispatch first
  const int rem = bid & 63;
  const int c = rem >> 5;           // key chunk 0/1
  const int hb = rem & 31;
  const int h = hb >> 1, b = hb & 1;
  const int rw0 = qx * 128 + wid * 32;
  const int qrow = rw0 + l31;
  const float NEGINF = -__builtin_inff();

  const int cnt = qx + 1;           // tiles in this chunk
  const int kt0 = c * cnt;          // first tile
  const int p = ((b * NH + h) * 32) + qx * 2 + c;  // partial index

  // Q B-fragments (col = q = lane&31): 4 a-blocks of 16
  bf16x8 qf[4];
#pragma unroll
  for (int ka = 0; ka < 4; ++ka)
    qf[ka] = *(const bf16x8*)(Q + (size_t)(b * S_LEN + qrow) * DIM + h * HD + ka * 16 + hi * 8);

  f32x16 oacc[2] = {};
  float rsA[4] = {0.f, 0.f, 0.f, 0.f};

  auto stage = [&](int buf, int kt) {
#pragma unroll
    for (int j = 0; j < 2; ++j) {
      int ob = (wid * 2 + j) * 1024;
      int o = ob + lane * 16;
      int r = o >> 7;
      int sb = (o & 127) ^ ((r & 7) << 4);
      gload_lds16(KV + (size_t)(b * S_LEN + kt * 64 + r) * (2 * DIM) + h * HD + (sb >> 1),
                  (char*)Kls[buf] + ob);
      gload_lds16(Vt + (size_t)((b * NH + h) * HD + r) * S_LEN + kt * 64 + (sb >> 1),
                  (char*)Vls[buf] + ob);
    }
  };

  stage(0, kt0);
  if (cnt > 1) stage(1, kt0 + 1);

  for (int i = 0; i < cnt; ++i) {
    const int kt = kt0 + i;
    if (i + 1 < cnt) asm volatile("s_waitcnt vmcnt(4)" ::: "memory");
    else             asm volatile("s_waitcnt vmcnt(0)" ::: "memory");
    __syncthreads();

    const int cb = i % 3;
    if (64 * kt <= rw0 + 31) {  // skip fully-masked tiles for this wave
      const bf16* Kb = Kls[cb];
      const bf16* Vb = Vls[cb];
      const bool maskt = (64 * kt + 63 > rw0);

#pragma unroll
      for (int kb = 0; kb < 2; ++kb) {
        // ---- S^T = K Q^T over this 32-key block ----
        f32x16 cc = {};
        __builtin_amdgcn_s_setprio(1);
#pragma unroll
        for (int ka = 0; ka < 4; ++ka) {
          int row = kb * 32 + l31;
          bf16x8 kf = *(const bf16x8*)((const char*)Kb + row * 128 +
                                       ((ka * 32 + hi * 16) ^ ((row & 7) << 4)));
          cc = __builtin_amdgcn_mfma_f32_32x32x16_bf16(kf, qf[ka], cc, 0, 0, 0);
        }
        __builtin_amdgcn_s_setprio(0);

        // ---- P = exp2(S); 4-way split row-sum accumulators ----
        float pe[16];
        if (maskt) {
#pragma unroll
          for (int r = 0; r < 16; ++r) {
            int key = kt * 64 + kb * 32 + (r & 3) + 8 * (r >> 2) + 4 * hi;
            float s = (key <= qrow) ? cc[r] : NEGINF;
            pe[r] = __builtin_amdgcn_exp2f(s);
            rsA[r & 3] += pe[r];
          }
        } else {
#pragma unroll
          for (int r = 0; r < 16; ++r) {
            pe[r] = __builtin_amdgcn_exp2f(cc[r]);
            rsA[r & 3] += pe[r];
          }
        }

        // ---- pack to bf16; half-wave exchange; PV A-frags in registers ----
        int u[8], x[8];
#pragma unroll
        for (int t = 0; t < 8; ++t) u[t] = cvt_pk_bf16(pe[2 * t], pe[2 * t + 1]);
#pragma unroll
        for (int t = 0; t < 8; ++t) x[t] = __shfl_xor(u[t], 32);
        i32x4 w0, w1;
        w0[0] = hi ? x[2] : u[0]; w0[1] = hi ? x[3] : u[1];
        w0[2] = hi ? u[2] : x[0]; w0[3] = hi ? u[3] : x[1];
        w1[0] = hi ? x[6] : u[4]; w1[1] = hi ? x[7] : u[5];
        w1[2] = hi ? u[6] : x[4]; w1[3] = hi ? u[7] : x[5];
        bf16x8 pa0 = as_bf16x8(w0), pa1 = as_bf16x8(w1);

        // ---- PV: O += P * V ----
        __builtin_amdgcn_s_setprio(1);
#pragma unroll
        for (int pl = 0; pl < 2; ++pl) {
          bf16x8 pa = pl ? pa1 : pa0;
#pragma unroll
          for (int nb = 0; nb < 2; ++nb) {
            int a = nb * 32 + l31;
            bf16x8 vf = *(const bf16x8*)((const char*)Vb + a * 128 +
                                         ((kb * 64 + pl * 32 + hi * 16) ^ ((a & 7) << 4)));
            oacc[nb] = __builtin_amdgcn_mfma_f32_32x32x16_bf16(pa, vf, oacc[nb], 0, 0, 0);
          }
        }
        __builtin_amdgcn_s_setprio(0);
      }
    }

    if (i + 2 < cnt) stage((i + 2) % 3, kt0 + i + 2);
  }

  // ---- write partials: unnormalized O (bf16) + row sums (fp32) ----
  float rsum = (rsA[0] + rsA[1]) + (rsA[2] + rsA[3]);
  rsum += __shfl_xor(rsum, 32);
  if (hi == 0) Rpart[p * 128 + wid * 32 + l31] = rsum;
#pragma unroll
  for (int nb = 0; nb < 2; ++nb)
#pragma unroll
    for (int r = 0; r < 16; ++r) {
      int qloc = (r & 3) + 8 * (r >> 2) + 4 * hi;
      Opart[(size_t)p * 8192 + (wid * 32 + qloc) * 64 + nb * 32 + l31] =
          __float2bfloat16(oacc[nb][r]);
    }
}

// ---------------- combine: O = (O0 + O1) / (r0 + r1) ----------------
__global__ __launch_bounds__(256) void attn_combine(
    const bf16* __restrict__ Opart, const float* __restrict__ Rpart,
    bf16* __restrict__ O) {
  const int g = blockIdx.x;          // (b*NH+h)*16 + qx
  const int qx = g & 15, bh = g >> 4;
  const int h = bh & 15, b = bh >> 4;
  const int t = threadIdx.x;
  const int row = t >> 1, col0 = (t & 1) * 32;
  const int p0 = bh * 32 + qx * 2;
  const size_t o0 = (size_t)p0 * 8192 + row * 64 + col0;
  const float rinv = 1.0f / (Rpart[p0 * 128 + row] + Rpart[p0 * 128 + 128 + row]);
  const int s = qx * 128 + row;
  bf16* dst = O + (size_t)(b * S_LEN + s) * DIM + h * HD + col0;
#pragma unroll
  for (int j = 0; j < 4; ++j) {
    bf16x8 a = *(const bf16x8*)(Opart + o0 + j * 8);
    bf16x8 cc = *(const bf16x8*)(Opart + o0 + 8192 + j * 8);
    bf16x8 w;
#pragma unroll
    for (int e = 0; e < 8; ++e) {
      bf16 r = __float2bfloat16((b2f(a[e]) + b2f(cc[e])) * rinv);
      ((short*)&w)[e] = *(short*)&r;
    }
    *(bf16x8*)(dst + j * 8) = w;
  }
}

// ---------------- launch ----------------
extern "C" void kernel_launch(void* const* d_in, const int* in_sizes, int n_in,
                              void* d_out, int out_size, void* d_ws, size_t ws_size,
                              hipStream_t stream) {
  (void)in_sizes; (void)n_in; (void)out_size; (void)ws_size;
  const float* query   = (const float*)d_in[0];
  const float* context = (const float*)d_in[1];
  const float* Wq      = (const float*)d_in[2];
  const float* Wkv     = (const float*)d_in[3];
  const float* Wout    = (const float*)d_in[4];
  float* out = (float*)d_out;

  bf16* ws = (bf16*)d_ws;
  const size_t nBSD = (size_t)BATCH * S_LEN * DIM;  // 4194304
  bf16* qbf    = ws;
  bf16* cbf    = qbf + nBSD;
  bf16* wqbf   = cbf + nBSD;
  bf16* wkvbf  = wqbf + (size_t)DIM * DIM;
  bf16* woutbf = wkvbf + (size_t)2 * DIM * DIM;
  bf16* Qp     = woutbf + (size_t)DIM * DIM;
  bf16* KVp    = Qp + nBSD;
  bf16* Vtp    = KVp + 2 * nBSD;
  bf16* Op     = Vtp + nBSD;
  // after gemm_proj, qbf/cbf/wqbf are dead -> reuse for attention partials
  bf16*  Opart = qbf;            // 1024*128*64 bf16 = 16.8 MB (qbf+cbf exactly)
  float* Rpart = (float*)wqbf;   // 1024*128 fp32 = 512 KB (wqbf exactly)

  // fused conversions
  cvt_all<<<2048, 256, 0, stream>>>(query, context, Wq, Wkv, Wout,
                                    qbf, cbf, wqbf, wkvbf, woutbf);

  // Q-proj (scaled by log2e/sqrt(D)) + KV-proj grouped: 768 blocks
  gemm_proj<<<768, 256, 0, stream>>>(qbf, wqbf, Qp, cbf, wkvbf, KVp, 0.0450842200277801f);

  // Vt
  transpose_v<<<dim3(S_LEN / 64, NH, BATCH), 256, 0, stream>>>(KVp, Vtp);
  // attention: 1024 key-split blocks, heavy-first
  attn_fwd<<<1024, 256, 0, stream>>>(Qp, KVp, Vtp, Opart, Rpart);
  // combine partials -> Op
  attn_combine<<<512, 256, 0, stream>>>(Opart, Rpart, Op);
  // out = O * Wout^T  (BN=64 -> 512 blocks)
  const int M = BATCH * S_LEN;
  gemm_bt_n64<<<dim3(DIM / 64, M / 128), 256, 0, stream>>>(Op, woutbf, out, M, DIM, DIM);
}